// Round 6
// baseline (519.549 us; speedup 1.0000x reference)
//
#include <hip/hip_runtime.h>
#include <stdint.h>

#define S_LEN 2048
#define NH 16
#define EMB 1024

typedef __attribute__((ext_vector_type(8))) short bf16x8;
typedef __attribute__((ext_vector_type(4))) float floatx4;
typedef const __attribute__((address_space(1))) unsigned int* gas_u32p;
typedef __attribute__((address_space(3))) unsigned int* las_u32p;

static __device__ __forceinline__ void gld_lds16(const void* g, void* l) {
  __builtin_amdgcn_global_load_lds((gas_u32p)g, (las_u32p)l, 16, 0, 0);
}

static __device__ __forceinline__ unsigned short f2bf(float f) {
  unsigned int u = __float_as_uint(f);
  unsigned int r = (u + 0x7FFFu + ((u >> 16) & 1u)) >> 16;
  return (unsigned short)r;
}
static __device__ __forceinline__ unsigned short f2bf_fast(float f) {
  return (unsigned short)((__float_as_uint(f) + 0x8000u) >> 16);
}

// ---------------- cast X f32 -> bf16 ----------------
__global__ void cast_x_kernel(const float* __restrict__ x, unsigned short* __restrict__ out, int n4) {
  int i = blockIdx.x * blockDim.x + threadIdx.x;
  if (i >= n4) return;
  float4 v = ((const float4*)x)[i];
  ushort4 o;
  o.x = f2bf(v.x); o.y = f2bf(v.y); o.z = f2bf(v.z); o.w = f2bf(v.w);
  ((ushort4*)out)[i] = o;
}

// ---------------- transpose+cast up to 3 weights f32 -> WT bf16 ----------------
__global__ void transpose_cast3(const float* __restrict__ W0, const float* __restrict__ W1,
                                const float* __restrict__ W2, unsigned short* __restrict__ out) {
  __shared__ float tile[32][33];
  const float* in = (blockIdx.z == 0) ? W0 : ((blockIdx.z == 1) ? W1 : W2);
  unsigned short* o = out + (size_t)blockIdx.z * 1048576;
  int x = blockIdx.x * 32 + threadIdx.x;
  int y0 = blockIdx.y * 32 + threadIdx.y;
#pragma unroll
  for (int j = 0; j < 4; j++)
    tile[threadIdx.y + 8 * j][threadIdx.x] = in[(y0 + 8 * j) * EMB + x];
  __syncthreads();
  int x2 = blockIdx.y * 32 + threadIdx.x;
  int y2 = blockIdx.x * 32 + threadIdx.y;
#pragma unroll
  for (int j = 0; j < 4; j++)
    o[(y2 + 8 * j) * EMB + x2] = f2bf(tile[threadIdx.x][threadIdx.y + 8 * j]);
}

// ---------------- bias LUT: lut[h][delta+2048] ----------------
__global__ void build_lut_kernel(const float* __restrict__ rel_emb, float* __restrict__ lut) {
  int idx = blockIdx.x * blockDim.x + threadIdx.x;
  if (idx >= 4096) return;
  int delta = idx - 2048;
  int bucket = (delta > 0) ? 16 : 0;
  int rp = (delta < 0) ? -delta : delta;
  int bl;
  if (rp < 8) bl = rp;
  else bl = 8 + (rp >= 12) + (rp >= 16) + (rp >= 23) + (rp >= 32) + (rp >= 46) + (rp >= 64) + (rp >= 91);
  bucket += bl;
#pragma unroll
  for (int h = 0; h < NH; h++)
    lut[h * 4096 + idx] = rel_emb[bucket * NH + h];
}

// ---------------- GEMM Q/K: C[M,2048] = Xb @ [Wq|Wk]^T, bf16 out [B,H,S,D] ----------------
__global__ __launch_bounds__(256) void gemm_qk(const unsigned short* __restrict__ A,
                                               const unsigned short* __restrict__ BT,
                                               unsigned short* __restrict__ oQ,
                                               unsigned short* __restrict__ oK) {
  __shared__ __align__(16) unsigned short As[128 * 64];
  __shared__ __align__(16) unsigned short Bs[128 * 64];
  const int tid = threadIdx.x;
  const int wave = tid >> 6, lane = tid & 63;
  const int quad = lane >> 4, lm = lane & 15;
  const int wm = wave & 1, wn = wave >> 1;
  const int mBase = blockIdx.y * 128, nBase = blockIdx.x * 128;
  const int gg = (lane & 7) ^ (lane >> 3);
  const int srow = lane >> 3;
  floatx4 acc[4][4];
#pragma unroll
  for (int i = 0; i < 4; i++)
#pragma unroll
    for (int j = 0; j < 4; j++) acc[i][j] = (floatx4){0.f, 0.f, 0.f, 0.f};

  for (int kt = 0; kt < 16; kt++) {
    int k0 = kt * 64;
    __syncthreads();
#pragma unroll
    for (int c = 0; c < 4; c++) {
      int chunk = wave * 4 + c;
      int row = chunk * 8 + srow;
      gld_lds16(&A[(size_t)(mBase + row) * 1024 + k0 + gg * 8], &As[chunk * 512]);
      gld_lds16(&BT[(size_t)(nBase + row) * 1024 + k0 + gg * 8], &Bs[chunk * 512]);
    }
    __syncthreads();
#pragma unroll
    for (int hh = 0; hh < 2; hh++) {
      bf16x8 af[4], bfr[4];
#pragma unroll
      for (int i = 0; i < 4; i++)
        af[i] = *(const bf16x8*)&As[(wm * 64 + i * 16 + lm) * 64 + (((hh << 2) + quad) ^ (lm & 7)) * 8];
#pragma unroll
      for (int j = 0; j < 4; j++)
        bfr[j] = *(const bf16x8*)&Bs[(wn * 64 + j * 16 + lm) * 64 + (((hh << 2) + quad) ^ (lm & 7)) * 8];
#pragma unroll
      for (int i = 0; i < 4; i++)
#pragma unroll
        for (int j = 0; j < 4; j++)
          acc[i][j] = __builtin_amdgcn_mfma_f32_16x16x32_bf16(af[i], bfr[j], acc[i][j], 0, 0, 0);
    }
  }
  const int which = nBase >> 10;
#pragma unroll
  for (int i = 0; i < 4; i++)
#pragma unroll
    for (int j = 0; j < 4; j++)
#pragma unroll
      for (int r = 0; r < 4; r++) {
        int row = mBase + wm * 64 + i * 16 + quad * 4 + r;
        int col = nBase + wn * 64 + j * 16 + lm;
        int b = row >> 11, s = row & 2047;
        int cw = col & 1023;
        int h = cw >> 6, d = cw & 63;
        unsigned short v = f2bf(acc[i][j][r]);
        if (which == 0) oQ[(((size_t)(b * NH + h) * S_LEN + s) * 64) + d] = v;
        else            oK[(((size_t)(b * NH + h) * S_LEN + s) * 64) + d] = v;
      }
}

// ---------------- GEMM V (operand-swapped): writes V^T [B,H,D,S] coalesced ----------------
__global__ __launch_bounds__(256) void gemm_v(const unsigned short* __restrict__ A,
                                              const unsigned short* __restrict__ BT,
                                              unsigned short* __restrict__ oV) {
  __shared__ __align__(16) unsigned short As[128 * 64];
  __shared__ __align__(16) unsigned short Bs[128 * 64];
  const int tid = threadIdx.x;
  const int wave = tid >> 6, lane = tid & 63;
  const int quad = lane >> 4, lm = lane & 15;
  const int wm = wave & 1, wn = wave >> 1;
  const int mBase = blockIdx.y * 128, nBase = blockIdx.x * 128;
  const int gg = (lane & 7) ^ (lane >> 3);
  const int srow = lane >> 3;
  floatx4 acc[4][4];
#pragma unroll
  for (int i = 0; i < 4; i++)
#pragma unroll
    for (int j = 0; j < 4; j++) acc[i][j] = (floatx4){0.f, 0.f, 0.f, 0.f};

  for (int kt = 0; kt < 16; kt++) {
    int k0 = kt * 64;
    __syncthreads();
#pragma unroll
    for (int c = 0; c < 4; c++) {
      int chunk = wave * 4 + c;
      int row = chunk * 8 + srow;
      gld_lds16(&A[(size_t)(mBase + row) * 1024 + k0 + gg * 8], &As[chunk * 512]);
      gld_lds16(&BT[(size_t)(nBase + row) * 1024 + k0 + gg * 8], &Bs[chunk * 512]);
    }
    __syncthreads();
#pragma unroll
    for (int hh = 0; hh < 2; hh++) {
      bf16x8 af[4], bfr[4];
#pragma unroll
      for (int i = 0; i < 4; i++)
        af[i] = *(const bf16x8*)&As[(wm * 64 + i * 16 + lm) * 64 + (((hh << 2) + quad) ^ (lm & 7)) * 8];
#pragma unroll
      for (int j = 0; j < 4; j++)
        bfr[j] = *(const bf16x8*)&Bs[(wn * 64 + j * 16 + lm) * 64 + (((hh << 2) + quad) ^ (lm & 7)) * 8];
#pragma unroll
      for (int i = 0; i < 4; i++)
#pragma unroll
        for (int j = 0; j < 4; j++)
          acc[i][j] = __builtin_amdgcn_mfma_f32_16x16x32_bf16(bfr[j], af[i], acc[i][j], 0, 0, 0);
    }
  }
#pragma unroll
  for (int i = 0; i < 4; i++)
#pragma unroll
    for (int j = 0; j < 4; j++)
#pragma unroll
      for (int r = 0; r < 4; r++) {
        int n = nBase + wn * 64 + j * 16 + quad * 4 + r;
        int m = mBase + wm * 64 + i * 16 + lm;
        int h = n >> 6, d = n & 63;
        int b = m >> 11, s = m & 2047;
        oV[(((size_t)(b * NH + h) * 64 + d) * S_LEN) + s] = f2bf(acc[i][j][r]);
      }
}

// ---------------- GEMM out-proj: f32 [M,1024] ----------------
__global__ __launch_bounds__(256) void gemm_out(const unsigned short* __restrict__ A,
                                                const unsigned short* __restrict__ BT,
                                                float* __restrict__ oF) {
  __shared__ __align__(16) unsigned short As[128 * 64];
  __shared__ __align__(16) unsigned short Bs[128 * 64];
  const int tid = threadIdx.x;
  const int wave = tid >> 6, lane = tid & 63;
  const int quad = lane >> 4, lm = lane & 15;
  const int wm = wave & 1, wn = wave >> 1;
  const int mBase = blockIdx.y * 128, nBase = blockIdx.x * 128;
  const int gg = (lane & 7) ^ (lane >> 3);
  const int srow = lane >> 3;
  floatx4 acc[4][4];
#pragma unroll
  for (int i = 0; i < 4; i++)
#pragma unroll
    for (int j = 0; j < 4; j++) acc[i][j] = (floatx4){0.f, 0.f, 0.f, 0.f};

  for (int kt = 0; kt < 16; kt++) {
    int k0 = kt * 64;
    __syncthreads();
#pragma unroll
    for (int c = 0; c < 4; c++) {
      int chunk = wave * 4 + c;
      int row = chunk * 8 + srow;
      gld_lds16(&A[(size_t)(mBase + row) * 1024 + k0 + gg * 8], &As[chunk * 512]);
      gld_lds16(&BT[(size_t)(nBase + row) * 1024 + k0 + gg * 8], &Bs[chunk * 512]);
    }
    __syncthreads();
#pragma unroll
    for (int hh = 0; hh < 2; hh++) {
      bf16x8 af[4], bfr[4];
#pragma unroll
      for (int i = 0; i < 4; i++)
        af[i] = *(const bf16x8*)&As[(wm * 64 + i * 16 + lm) * 64 + (((hh << 2) + quad) ^ (lm & 7)) * 8];
#pragma unroll
      for (int j = 0; j < 4; j++)
        bfr[j] = *(const bf16x8*)&Bs[(wn * 64 + j * 16 + lm) * 64 + (((hh << 2) + quad) ^ (lm & 7)) * 8];
#pragma unroll
      for (int i = 0; i < 4; i++)
#pragma unroll
        for (int j = 0; j < 4; j++)
          acc[i][j] = __builtin_amdgcn_mfma_f32_16x16x32_bf16(af[i], bfr[j], acc[i][j], 0, 0, 0);
    }
  }
#pragma unroll
  for (int i = 0; i < 4; i++)
#pragma unroll
    for (int j = 0; j < 4; j++)
#pragma unroll
      for (int r = 0; r < 4; r++) {
        int row = mBase + wm * 64 + i * 16 + quad * 4 + r;
        int col = nBase + wn * 64 + j * 16 + lm;
        oF[(size_t)row * 1024 + col] = acc[i][j][r];
      }
}

// ---------------- flash attention, 8 waves, in-block split-K + balanced bias write ----------------
// grid 512 (XCD swizzle). Block = (bh, 128-q tile). Waves 0-3: k in [0,1024); waves 4-7: [1024,2048).
// Bias: b==0 blocks write k-half 0, b==1 blocks write k-half 1 (balanced, normal stores -> L2 ack).
__global__ __launch_bounds__(512, 4) void attn_kernel(const unsigned short* __restrict__ Qb,
                                                      const unsigned short* __restrict__ Kb,
                                                      const unsigned short* __restrict__ Vtb,
                                                      const float* __restrict__ lut,
                                                      unsigned short* __restrict__ Ob,
                                                      float* __restrict__ bias_out) {
  __shared__ __align__(16) unsigned short Kl[2][64 * 64];
  __shared__ __align__(16) unsigned short Vl[2][64 * 64];
  __shared__ __align__(16) unsigned short Pl[8][16 * 72];
  const int tid = threadIdx.x;
  const int wave = tid >> 6, lane = tid & 63;
  const int quad = lane >> 4, lm = lane & 15;
  const int ws = wave & 3, half = wave >> 2;
  const int ii = blockIdx.x;
  const int bh = (ii & 7) * 4 + ((ii >> 3) & 3);
  const int qTile = (ii >> 5) * 128;
  const int b = bh >> 4, h = bh & 15;
  const unsigned short* Qp = Qb + (size_t)bh * S_LEN * 64;
  const unsigned short* Kp = Kb + (size_t)bh * S_LEN * 64;
  const unsigned short* Vp = Vtb + (size_t)bh * 64 * S_LEN;
  const float* lrow = lut + h * 4096;
  const float cneg = lrow[0], cpos = lrow[4095];
  const int gg = (lane & 7) ^ (lane >> 3);
  const int srow = lane >> 3;
  const int qw = qTile + ws * 32;

  bf16x8 aq[2][2];
#pragma unroll
  for (int g = 0; g < 2; g++)
#pragma unroll
    for (int hh = 0; hh < 2; hh++)
      aq[g][hh] = *(const bf16x8*)&Qp[(qw + g * 16 + lm) * 64 + hh * 32 + quad * 8];

  floatx4 accO[2][4];
#pragma unroll
  for (int g = 0; g < 2; g++)
#pragma unroll
    for (int d = 0; d < 4; d++) accO[g][d] = (floatx4){0.f, 0.f, 0.f, 0.f};
  float lp[2] = {0.f, 0.f};

  unsigned short* Pw = Pl[wave];

  for (int ktl = 0; ktl < 16; ktl++) {
    const int kBase = (half << 10) + ktl * 64;
    __syncthreads();
#pragma unroll
    for (int c = 0; c < 2; c++) {
      int chunk = ws * 2 + c;
      int row = chunk * 8 + srow;
      gld_lds16(&Kp[(size_t)(kBase + row) * 64 + gg * 8], &Kl[half][chunk * 512]);
      gld_lds16(&Vp[(size_t)row * S_LEN + kBase + gg * 8], &Vl[half][chunk * 512]);
    }
    __syncthreads();

    // balanced fused bias write: this block writes the (qTile, b-half) bias tiles
    {
      const int kW = (b << 10) + ktl * 64;
      const bool farW = (kW + 154 <= qTile) || (kW >= qTile + 218);
      float* bt = bias_out + ((size_t)(h * S_LEN + qTile)) * S_LEN + kW;
      if (farW) {
        const float cW = (kW < qTile) ? cneg : cpos;
        floatx4 cf4 = (floatx4){cW, cW, cW, cW};
#pragma unroll
        for (int e = 0; e < 4; e++) {
          int f = tid + e * 512;
          int qlo = f >> 4, kk = (f & 15) << 2;
          *(floatx4*)&bt[(size_t)qlo * S_LEN + kk] = cf4;
        }
      } else {
#pragma unroll
        for (int e = 0; e < 4; e++) {
          int f = tid + e * 512;
          int qlo = f >> 4, kk = (f & 15) << 2;
          const float* lr = lrow + (kW + kk) - (qTile + qlo) + 2048;
          *(floatx4*)&bt[(size_t)qlo * S_LEN + kk] = (floatx4){lr[0], lr[1], lr[2], lr[3]};
        }
      }
    }

    const bool farTile = (kBase + 154 <= qTile) || (kBase >= qTile + 218);
    const float cfar = (kBase < qTile) ? cneg : cpos;

    // S^T = K·Q^T : thread holds q=lm, k=nt*16+quad*4+r
    floatx4 s4[2][4];
#pragma unroll
    for (int nt = 0; nt < 4; nt++) {
      int rbase = (nt * 16 + lm) * 64;
      bf16x8 kf0 = *(const bf16x8*)&Kl[half][rbase + ((quad ^ (lm & 7)) << 3)];
      bf16x8 kf1 = *(const bf16x8*)&Kl[half][rbase + (((4 + quad) ^ (lm & 7)) << 3)];
#pragma unroll
      for (int g = 0; g < 2; g++) {
        floatx4 z = (floatx4){0.f, 0.f, 0.f, 0.f};
        z = __builtin_amdgcn_mfma_f32_16x16x32_bf16(kf0, aq[g][0], z, 0, 0, 0);
        z = __builtin_amdgcn_mfma_f32_16x16x32_bf16(kf1, aq[g][1], z, 0, 0, 0);
        s4[g][nt] = z;
      }
    }

    bf16x8 pa[2][2];
#pragma unroll
    for (int g = 0; g < 2; g++) {
      int q = qw + g * 16 + lm;
      float psum = 0.f;
#pragma unroll
      for (int nt = 0; nt < 4; nt++) {
        union { unsigned short u[4]; uint2 v; } pk;
#pragma unroll
        for (int r = 0; r < 4; r++) {
          float sv;
          if (farTile) sv = s4[g][nt][r] + cfar;
          else {
            int kcol = kBase + nt * 16 + quad * 4 + r;
            sv = s4[g][nt][r] + __ldg(&lrow[kcol - q + 2048]);
          }
          float p = __expf(sv);
          psum += p;
          pk.u[r] = f2bf_fast(p);
        }
        *(uint2*)&Pw[lm * 72 + nt * 16 + quad * 4] = pk.v;  // P[q=lm][k..k+3]
      }
      lp[g] += psum;
      // same-wave DS ordering: reads see this g's writes; next g overwrites after reads
      pa[g][0] = *(const bf16x8*)&Pw[lm * 72 + quad * 8];
      pa[g][1] = *(const bf16x8*)&Pw[lm * 72 + 32 + quad * 8];
    }

#pragma unroll
    for (int d = 0; d < 4; d++) {
      int rbase = (d * 16 + lm) * 64;
      bf16x8 vf0 = *(const bf16x8*)&Vl[half][rbase + ((quad ^ (lm & 7)) << 3)];
      bf16x8 vf1 = *(const bf16x8*)&Vl[half][rbase + (((4 + quad) ^ (lm & 7)) << 3)];
      accO[0][d] = __builtin_amdgcn_mfma_f32_16x16x32_bf16(pa[0][0], vf0, accO[0][d], 0, 0, 0);
      accO[0][d] = __builtin_amdgcn_mfma_f32_16x16x32_bf16(pa[0][1], vf1, accO[0][d], 0, 0, 0);
      accO[1][d] = __builtin_amdgcn_mfma_f32_16x16x32_bf16(pa[1][0], vf0, accO[1][d], 0, 0, 0);
      accO[1][d] = __builtin_amdgcn_mfma_f32_16x16x32_bf16(pa[1][1], vf1, accO[1][d], 0, 0, 0);
    }
  }

  // reduce row-sums across quads (within wave)
#pragma unroll
  for (int g = 0; g < 2; g++) {
    lp[g] += __shfl_xor(lp[g], 16, 64);
    lp[g] += __shfl_xor(lp[g], 32, 64);
  }

  __syncthreads();  // all k-loop LDS reads done; alias Kl/Vl as f32 exchange buffers
  float* Ox = (ws < 2) ? ((float*)&Kl[0][0]) + ws * 2048 : ((float*)&Vl[0][0]) + (ws - 2) * 2048;
  float* lpf = (float*)&Pl[0][0];
  if (half == 1) {
#pragma unroll
    for (int g = 0; g < 2; g++) {
#pragma unroll
      for (int d = 0; d < 4; d++)
#pragma unroll
        for (int r = 0; r < 4; r++)
          Ox[(g * 16 + quad * 4 + r) * 64 + d * 16 + lm] = accO[g][d][r];
      if (quad == 0) lpf[ws * 32 + g * 16 + lm] = lp[g];
    }
  }
  __syncthreads();
  if (half == 0) {
    float ltot[2];
#pragma unroll
    for (int g = 0; g < 2; g++) ltot[g] = lp[g] + lpf[ws * 32 + g * 16 + lm];
#pragma unroll
    for (int g = 0; g < 2; g++) {
      float linv[4];
#pragma unroll
      for (int r = 0; r < 4; r++) linv[r] = 1.f / __shfl(ltot[g], quad * 4 + r, 64);
#pragma unroll
      for (int d = 0; d < 4; d++)
#pragma unroll
        for (int r = 0; r < 4; r++) {
          float val = accO[g][d][r] + Ox[(g * 16 + quad * 4 + r) * 64 + d * 16 + lm];
          int q = qw + g * 16 + quad * 4 + r;
          int col = h * 64 + d * 16 + lm;
          Ob[((size_t)(b * S_LEN + q)) * 1024 + col] = f2bf_fast(val * linv[r]);
        }
    }
  }
}

extern "C" void kernel_launch(void* const* d_in, const int* in_sizes, int n_in,
                              void* d_out, int out_size, void* d_ws, size_t ws_size,
                              hipStream_t stream) {
  const float* X   = (const float*)d_in[0];
  const float* Wq  = (const float*)d_in[1];
  const float* Wk  = (const float*)d_in[2];
  const float* Wv  = (const float*)d_in[3];
  const float* Wo  = (const float*)d_in[4];
  const float* rel = (const float*)d_in[5];
  float* out = (float*)d_out;           // [2,2048,1024]
  float* bias_out = out + 4194304;      // [1,16,2048,2048]

  char* ws = (char*)d_ws;
  unsigned short* Xb    = (unsigned short*)(ws);
  unsigned short* WqkvT = (unsigned short*)(ws + (size_t)(8u  << 20));  // 3 x 2MB
  unsigned short* WoT   = (unsigned short*)(ws + (size_t)(14u << 20));
  unsigned short* Qb    = (unsigned short*)(ws + (size_t)(16u << 20));
  unsigned short* Kb    = (unsigned short*)(ws + (size_t)(24u << 20));
  unsigned short* Vtb   = (unsigned short*)(ws + (size_t)(32u << 20));
  unsigned short* Ob    = (unsigned short*)(ws + (size_t)(40u << 20));
  float* lut            = (float*)(ws + (size_t)(48u << 20));

  cast_x_kernel<<<4096, 256, 0, stream>>>(X, Xb, 1048576);
  dim3 tb(32, 8);
  transpose_cast3<<<dim3(32, 32, 3), tb, 0, stream>>>(Wq, Wk, Wv, WqkvT);
  transpose_cast3<<<dim3(32, 32, 1), tb, 0, stream>>>(Wo, Wo, Wo, WoT);
  build_lut_kernel<<<16, 256, 0, stream>>>(rel, lut);

  gemm_qk<<<dim3(16, 32), 256, 0, stream>>>(Xb, WqkvT, Qb, Kb);
  gemm_v<<<dim3(8, 32), 256, 0, stream>>>(Xb, WqkvT + 2 * 1048576, Vtb);
  attn_kernel<<<512, 512, 0, stream>>>(Qb, Kb, Vtb, lut, Ob, bias_out);
  gemm_out<<<dim3(8, 32), 256, 0, stream>>>(Ob, WoT, out);
}

// Round 7
// 452.377 us; speedup vs baseline: 1.1485x; 1.1485x over previous
//
#include <hip/hip_runtime.h>
#include <stdint.h>

#define S_LEN 2048
#define NH 16
#define EMB 1024

typedef __attribute__((ext_vector_type(8))) short bf16x8;
typedef __attribute__((ext_vector_type(4))) float floatx4;
typedef const __attribute__((address_space(1))) unsigned int* gas_u32p;
typedef __attribute__((address_space(3))) unsigned int* las_u32p;

static __device__ __forceinline__ void gld_lds16(const void* g, void* l) {
  __builtin_amdgcn_global_load_lds((gas_u32p)g, (las_u32p)l, 16, 0, 0);
}

static __device__ __forceinline__ unsigned short f2bf(float f) {
  unsigned int u = __float_as_uint(f);
  unsigned int r = (u + 0x7FFFu + ((u >> 16) & 1u)) >> 16;
  return (unsigned short)r;
}
static __device__ __forceinline__ unsigned short f2bf_fast(float f) {
  return (unsigned short)((__float_as_uint(f) + 0x8000u) >> 16);
}

// ---------------- cast X f32 -> bf16 ----------------
__global__ void cast_x_kernel(const float* __restrict__ x, unsigned short* __restrict__ out, int n4) {
  int i = blockIdx.x * blockDim.x + threadIdx.x;
  if (i >= n4) return;
  float4 v = ((const float4*)x)[i];
  ushort4 o;
  o.x = f2bf(v.x); o.y = f2bf(v.y); o.z = f2bf(v.z); o.w = f2bf(v.w);
  ((ushort4*)out)[i] = o;
}

// ---------------- transpose+cast up to 3 weights f32 -> WT bf16 ----------------
__global__ void transpose_cast3(const float* __restrict__ W0, const float* __restrict__ W1,
                                const float* __restrict__ W2, unsigned short* __restrict__ out) {
  __shared__ float tile[32][33];
  const float* in = (blockIdx.z == 0) ? W0 : ((blockIdx.z == 1) ? W1 : W2);
  unsigned short* o = out + (size_t)blockIdx.z * 1048576;
  int x = blockIdx.x * 32 + threadIdx.x;
  int y0 = blockIdx.y * 32 + threadIdx.y;
#pragma unroll
  for (int j = 0; j < 4; j++)
    tile[threadIdx.y + 8 * j][threadIdx.x] = in[(y0 + 8 * j) * EMB + x];
  __syncthreads();
  int x2 = blockIdx.y * 32 + threadIdx.x;
  int y2 = blockIdx.x * 32 + threadIdx.y;
#pragma unroll
  for (int j = 0; j < 4; j++)
    o[(y2 + 8 * j) * EMB + x2] = f2bf(tile[threadIdx.x][threadIdx.y + 8 * j]);
}

// ---------------- bias LUT: lut[h][delta+2048] ----------------
__global__ void build_lut_kernel(const float* __restrict__ rel_emb, float* __restrict__ lut) {
  int idx = blockIdx.x * blockDim.x + threadIdx.x;
  if (idx >= 4096) return;
  int delta = idx - 2048;
  int bucket = (delta > 0) ? 16 : 0;
  int rp = (delta < 0) ? -delta : delta;
  int bl;
  if (rp < 8) bl = rp;
  else bl = 8 + (rp >= 12) + (rp >= 16) + (rp >= 23) + (rp >= 32) + (rp >= 46) + (rp >= 64) + (rp >= 91);
  bucket += bl;
#pragma unroll
  for (int h = 0; h < NH; h++)
    lut[h * 4096 + idx] = rel_emb[bucket * NH + h];
}

// ---------------- position_bias writer: [16,2048,2048] f32 (write-roofline) ----------------
__global__ void bias_out_kernel(const float* __restrict__ lut, float* __restrict__ dst) {
  int i = blockIdx.x * blockDim.x + threadIdx.x;
  int h = i >> 20;
  int rem = i & 1048575;
  int q = rem >> 9;
  int k4 = (rem & 511) << 2;
  const float* lr = lut + h * 4096 + (k4 - q + 2048);
  float4 v = make_float4(__ldg(lr), __ldg(lr + 1), __ldg(lr + 2), __ldg(lr + 3));
  ((float4*)dst)[i] = v;
}

// ---------------- GEMM Q/K: C[M,2048] = Xb @ [Wq|Wk]^T, bf16 out [B,H,S,D] ----------------
__global__ __launch_bounds__(256) void gemm_qk(const unsigned short* __restrict__ A,
                                               const unsigned short* __restrict__ BT,
                                               unsigned short* __restrict__ oQ,
                                               unsigned short* __restrict__ oK) {
  __shared__ __align__(16) unsigned short As[128 * 64];
  __shared__ __align__(16) unsigned short Bs[128 * 64];
  const int tid = threadIdx.x;
  const int wave = tid >> 6, lane = tid & 63;
  const int quad = lane >> 4, lm = lane & 15;
  const int wm = wave & 1, wn = wave >> 1;
  const int mBase = blockIdx.y * 128, nBase = blockIdx.x * 128;
  const int gg = (lane & 7) ^ (lane >> 3);
  const int srow = lane >> 3;
  floatx4 acc[4][4];
#pragma unroll
  for (int i = 0; i < 4; i++)
#pragma unroll
    for (int j = 0; j < 4; j++) acc[i][j] = (floatx4){0.f, 0.f, 0.f, 0.f};

  for (int kt = 0; kt < 16; kt++) {
    int k0 = kt * 64;
    __syncthreads();
#pragma unroll
    for (int c = 0; c < 4; c++) {
      int chunk = wave * 4 + c;
      int row = chunk * 8 + srow;
      gld_lds16(&A[(size_t)(mBase + row) * 1024 + k0 + gg * 8], &As[chunk * 512]);
      gld_lds16(&BT[(size_t)(nBase + row) * 1024 + k0 + gg * 8], &Bs[chunk * 512]);
    }
    __syncthreads();
#pragma unroll
    for (int hh = 0; hh < 2; hh++) {
      bf16x8 af[4], bfr[4];
#pragma unroll
      for (int i = 0; i < 4; i++)
        af[i] = *(const bf16x8*)&As[(wm * 64 + i * 16 + lm) * 64 + (((hh << 2) + quad) ^ (lm & 7)) * 8];
#pragma unroll
      for (int j = 0; j < 4; j++)
        bfr[j] = *(const bf16x8*)&Bs[(wn * 64 + j * 16 + lm) * 64 + (((hh << 2) + quad) ^ (lm & 7)) * 8];
#pragma unroll
      for (int i = 0; i < 4; i++)
#pragma unroll
        for (int j = 0; j < 4; j++)
          acc[i][j] = __builtin_amdgcn_mfma_f32_16x16x32_bf16(af[i], bfr[j], acc[i][j], 0, 0, 0);
    }
  }
  const int which = nBase >> 10;
#pragma unroll
  for (int i = 0; i < 4; i++)
#pragma unroll
    for (int j = 0; j < 4; j++)
#pragma unroll
      for (int r = 0; r < 4; r++) {
        int row = mBase + wm * 64 + i * 16 + quad * 4 + r;
        int col = nBase + wn * 64 + j * 16 + lm;
        int b = row >> 11, s = row & 2047;
        int cw = col & 1023;
        int h = cw >> 6, d = cw & 63;
        unsigned short v = f2bf(acc[i][j][r]);
        if (which == 0) oQ[(((size_t)(b * NH + h) * S_LEN + s) * 64) + d] = v;
        else            oK[(((size_t)(b * NH + h) * S_LEN + s) * 64) + d] = v;
      }
}

// ---------------- GEMM V (operand-swapped): writes V^T [B,H,D,S] coalesced ----------------
__global__ __launch_bounds__(256) void gemm_v(const unsigned short* __restrict__ A,
                                              const unsigned short* __restrict__ BT,
                                              unsigned short* __restrict__ oV) {
  __shared__ __align__(16) unsigned short As[128 * 64];
  __shared__ __align__(16) unsigned short Bs[128 * 64];
  const int tid = threadIdx.x;
  const int wave = tid >> 6, lane = tid & 63;
  const int quad = lane >> 4, lm = lane & 15;
  const int wm = wave & 1, wn = wave >> 1;
  const int mBase = blockIdx.y * 128, nBase = blockIdx.x * 128;
  const int gg = (lane & 7) ^ (lane >> 3);
  const int srow = lane >> 3;
  floatx4 acc[4][4];
#pragma unroll
  for (int i = 0; i < 4; i++)
#pragma unroll
    for (int j = 0; j < 4; j++) acc[i][j] = (floatx4){0.f, 0.f, 0.f, 0.f};

  for (int kt = 0; kt < 16; kt++) {
    int k0 = kt * 64;
    __syncthreads();
#pragma unroll
    for (int c = 0; c < 4; c++) {
      int chunk = wave * 4 + c;
      int row = chunk * 8 + srow;
      gld_lds16(&A[(size_t)(mBase + row) * 1024 + k0 + gg * 8], &As[chunk * 512]);
      gld_lds16(&BT[(size_t)(nBase + row) * 1024 + k0 + gg * 8], &Bs[chunk * 512]);
    }
    __syncthreads();
#pragma unroll
    for (int hh = 0; hh < 2; hh++) {
      bf16x8 af[4], bfr[4];
#pragma unroll
      for (int i = 0; i < 4; i++)
        af[i] = *(const bf16x8*)&As[(wm * 64 + i * 16 + lm) * 64 + (((hh << 2) + quad) ^ (lm & 7)) * 8];
#pragma unroll
      for (int j = 0; j < 4; j++)
        bfr[j] = *(const bf16x8*)&Bs[(wn * 64 + j * 16 + lm) * 64 + (((hh << 2) + quad) ^ (lm & 7)) * 8];
#pragma unroll
      for (int i = 0; i < 4; i++)
#pragma unroll
        for (int j = 0; j < 4; j++)
          acc[i][j] = __builtin_amdgcn_mfma_f32_16x16x32_bf16(bfr[j], af[i], acc[i][j], 0, 0, 0);
    }
  }
#pragma unroll
  for (int i = 0; i < 4; i++)
#pragma unroll
    for (int j = 0; j < 4; j++)
#pragma unroll
      for (int r = 0; r < 4; r++) {
        int n = nBase + wn * 64 + j * 16 + quad * 4 + r;
        int m = mBase + wm * 64 + i * 16 + lm;
        int h = n >> 6, d = n & 63;
        int b = m >> 11, s = m & 2047;
        oV[(((size_t)(b * NH + h) * 64 + d) * S_LEN) + s] = f2bf(acc[i][j][r]);
      }
}

// ---------------- GEMM out-proj: f32 [M,1024] ----------------
__global__ __launch_bounds__(256) void gemm_out(const unsigned short* __restrict__ A,
                                                const unsigned short* __restrict__ BT,
                                                float* __restrict__ oF) {
  __shared__ __align__(16) unsigned short As[128 * 64];
  __shared__ __align__(16) unsigned short Bs[128 * 64];
  const int tid = threadIdx.x;
  const int wave = tid >> 6, lane = tid & 63;
  const int quad = lane >> 4, lm = lane & 15;
  const int wm = wave & 1, wn = wave >> 1;
  const int mBase = blockIdx.y * 128, nBase = blockIdx.x * 128;
  const int gg = (lane & 7) ^ (lane >> 3);
  const int srow = lane >> 3;
  floatx4 acc[4][4];
#pragma unroll
  for (int i = 0; i < 4; i++)
#pragma unroll
    for (int j = 0; j < 4; j++) acc[i][j] = (floatx4){0.f, 0.f, 0.f, 0.f};

  for (int kt = 0; kt < 16; kt++) {
    int k0 = kt * 64;
    __syncthreads();
#pragma unroll
    for (int c = 0; c < 4; c++) {
      int chunk = wave * 4 + c;
      int row = chunk * 8 + srow;
      gld_lds16(&A[(size_t)(mBase + row) * 1024 + k0 + gg * 8], &As[chunk * 512]);
      gld_lds16(&BT[(size_t)(nBase + row) * 1024 + k0 + gg * 8], &Bs[chunk * 512]);
    }
    __syncthreads();
#pragma unroll
    for (int hh = 0; hh < 2; hh++) {
      bf16x8 af[4], bfr[4];
#pragma unroll
      for (int i = 0; i < 4; i++)
        af[i] = *(const bf16x8*)&As[(wm * 64 + i * 16 + lm) * 64 + (((hh << 2) + quad) ^ (lm & 7)) * 8];
#pragma unroll
      for (int j = 0; j < 4; j++)
        bfr[j] = *(const bf16x8*)&Bs[(wn * 64 + j * 16 + lm) * 64 + (((hh << 2) + quad) ^ (lm & 7)) * 8];
#pragma unroll
      for (int i = 0; i < 4; i++)
#pragma unroll
        for (int j = 0; j < 4; j++)
          acc[i][j] = __builtin_amdgcn_mfma_f32_16x16x32_bf16(af[i], bfr[j], acc[i][j], 0, 0, 0);
    }
  }
#pragma unroll
  for (int i = 0; i < 4; i++)
#pragma unroll
    for (int j = 0; j < 4; j++)
#pragma unroll
      for (int r = 0; r < 4; r++) {
        int row = mBase + wm * 64 + i * 16 + quad * 4 + r;
        int col = nBase + wn * 64 + j * 16 + lm;
        oF[(size_t)row * 1024 + col] = acc[i][j][r];
      }
}

// ---------------- flash attention, 8 waves, in-block split-K (no bias write) ----------------
// grid 512 (XCD swizzle). Block = (bh, 128-q tile). Waves 0-3: k in [0,1024); waves 4-7: [1024,2048).
// Near-tile bias adds read a 512-entry LDS window of the LUT (|k-q| <= 255 on near tiles).
__global__ __launch_bounds__(512, 4) void attn_kernel(const unsigned short* __restrict__ Qb,
                                                      const unsigned short* __restrict__ Kb,
                                                      const unsigned short* __restrict__ Vtb,
                                                      const float* __restrict__ lut,
                                                      unsigned short* __restrict__ Ob) {
  __shared__ __align__(16) unsigned short Kl[2][64 * 64];
  __shared__ __align__(16) unsigned short Vl[2][64 * 64];
  __shared__ __align__(16) unsigned short Pl[8][16 * 72];
  __shared__ float lutS[512];
  const int tid = threadIdx.x;
  const int wave = tid >> 6, lane = tid & 63;
  const int quad = lane >> 4, lm = lane & 15;
  const int ws = wave & 3, half = wave >> 2;
  const int ii = blockIdx.x;
  const int bh = (ii & 7) * 4 + ((ii >> 3) & 3);
  const int qTile = (ii >> 5) * 128;
  const int b = bh >> 4, h = bh & 15;
  const unsigned short* Qp = Qb + (size_t)bh * S_LEN * 64;
  const unsigned short* Kp = Kb + (size_t)bh * S_LEN * 64;
  const unsigned short* Vp = Vtb + (size_t)bh * 64 * S_LEN;
  const float* lrow = lut + h * 4096;
  const float cneg = lrow[0], cpos = lrow[4095];
  const int gg = (lane & 7) ^ (lane >> 3);
  const int srow = lane >> 3;
  const int qw = qTile + ws * 32;

  if (tid < 512) lutS[tid] = lrow[2048 - 256 + tid];  // deltas [-256, 255]

  bf16x8 aq[2][2];
#pragma unroll
  for (int g = 0; g < 2; g++)
#pragma unroll
    for (int hh = 0; hh < 2; hh++)
      aq[g][hh] = *(const bf16x8*)&Qp[(qw + g * 16 + lm) * 64 + hh * 32 + quad * 8];

  floatx4 accO[2][4];
#pragma unroll
  for (int g = 0; g < 2; g++)
#pragma unroll
    for (int d = 0; d < 4; d++) accO[g][d] = (floatx4){0.f, 0.f, 0.f, 0.f};
  float lp[2] = {0.f, 0.f};

  unsigned short* Pw = Pl[wave];

  for (int ktl = 0; ktl < 16; ktl++) {
    const int kBase = (half << 10) + ktl * 64;
    __syncthreads();
#pragma unroll
    for (int c = 0; c < 2; c++) {
      int chunk = ws * 2 + c;
      int row = chunk * 8 + srow;
      gld_lds16(&Kp[(size_t)(kBase + row) * 64 + gg * 8], &Kl[half][chunk * 512]);
      gld_lds16(&Vp[(size_t)row * S_LEN + kBase + gg * 8], &Vl[half][chunk * 512]);
    }
    __syncthreads();

    const bool farTile = (kBase + 154 <= qTile) || (kBase >= qTile + 218);
    const float cfar = (kBase < qTile) ? cneg : cpos;

    // S^T = K·Q^T : thread holds q=lm, k=nt*16+quad*4+r
    floatx4 s4[2][4];
#pragma unroll
    for (int nt = 0; nt < 4; nt++) {
      int rbase = (nt * 16 + lm) * 64;
      bf16x8 kf0 = *(const bf16x8*)&Kl[half][rbase + ((quad ^ (lm & 7)) << 3)];
      bf16x8 kf1 = *(const bf16x8*)&Kl[half][rbase + (((4 + quad) ^ (lm & 7)) << 3)];
#pragma unroll
      for (int g = 0; g < 2; g++) {
        floatx4 z = (floatx4){0.f, 0.f, 0.f, 0.f};
        z = __builtin_amdgcn_mfma_f32_16x16x32_bf16(kf0, aq[g][0], z, 0, 0, 0);
        z = __builtin_amdgcn_mfma_f32_16x16x32_bf16(kf1, aq[g][1], z, 0, 0, 0);
        s4[g][nt] = z;
      }
    }

    bf16x8 pa[2][2];
#pragma unroll
    for (int g = 0; g < 2; g++) {
      // base LDS-lut index for this thread/group: delta = kcol - q, idx = delta + 256
      const int b0 = kBase + quad * 4 - (qw + g * 16 + lm) + 256;
      float psum = 0.f;
#pragma unroll
      for (int nt = 0; nt < 4; nt++) {
        union { unsigned short u[4]; uint2 v; } pk;
#pragma unroll
        for (int r = 0; r < 4; r++) {
          float sv;
          if (farTile) sv = s4[g][nt][r] + cfar;
          else         sv = s4[g][nt][r] + lutS[b0 + nt * 16 + r];
          float p = __expf(sv);
          psum += p;
          pk.u[r] = f2bf_fast(p);
        }
        *(uint2*)&Pw[lm * 72 + nt * 16 + quad * 4] = pk.v;  // P[q=lm][k..k+3]
      }
      lp[g] += psum;
      // same-wave DS ordering: reads see this g's writes; next g overwrites after reads
      pa[g][0] = *(const bf16x8*)&Pw[lm * 72 + quad * 8];
      pa[g][1] = *(const bf16x8*)&Pw[lm * 72 + 32 + quad * 8];
    }

#pragma unroll
    for (int d = 0; d < 4; d++) {
      int rbase = (d * 16 + lm) * 64;
      bf16x8 vf0 = *(const bf16x8*)&Vl[half][rbase + ((quad ^ (lm & 7)) << 3)];
      bf16x8 vf1 = *(const bf16x8*)&Vl[half][rbase + (((4 + quad) ^ (lm & 7)) << 3)];
      accO[0][d] = __builtin_amdgcn_mfma_f32_16x16x32_bf16(pa[0][0], vf0, accO[0][d], 0, 0, 0);
      accO[0][d] = __builtin_amdgcn_mfma_f32_16x16x32_bf16(pa[0][1], vf1, accO[0][d], 0, 0, 0);
      accO[1][d] = __builtin_amdgcn_mfma_f32_16x16x32_bf16(pa[1][0], vf0, accO[1][d], 0, 0, 0);
      accO[1][d] = __builtin_amdgcn_mfma_f32_16x16x32_bf16(pa[1][1], vf1, accO[1][d], 0, 0, 0);
    }
  }

  // reduce row-sums across quads (within wave)
#pragma unroll
  for (int g = 0; g < 2; g++) {
    lp[g] += __shfl_xor(lp[g], 16, 64);
    lp[g] += __shfl_xor(lp[g], 32, 64);
  }

  __syncthreads();  // all k-loop LDS reads done; alias Kl/Vl as f32 exchange buffers
  float* Ox = (ws < 2) ? ((float*)&Kl[0][0]) + ws * 2048 : ((float*)&Vl[0][0]) + (ws - 2) * 2048;
  float* lpf = (float*)&Pl[0][0];
  if (half == 1) {
#pragma unroll
    for (int g = 0; g < 2; g++) {
#pragma unroll
      for (int d = 0; d < 4; d++)
#pragma unroll
        for (int r = 0; r < 4; r++)
          Ox[(g * 16 + quad * 4 + r) * 64 + d * 16 + lm] = accO[g][d][r];
      if (quad == 0) lpf[ws * 32 + g * 16 + lm] = lp[g];
    }
  }
  __syncthreads();
  if (half == 0) {
    float ltot[2];
#pragma unroll
    for (int g = 0; g < 2; g++) ltot[g] = lp[g] + lpf[ws * 32 + g * 16 + lm];
#pragma unroll
    for (int g = 0; g < 2; g++) {
      float linv[4];
#pragma unroll
      for (int r = 0; r < 4; r++) linv[r] = 1.f / __shfl(ltot[g], quad * 4 + r, 64);
#pragma unroll
      for (int d = 0; d < 4; d++)
#pragma unroll
        for (int r = 0; r < 4; r++) {
          float val = accO[g][d][r] + Ox[(g * 16 + quad * 4 + r) * 64 + d * 16 + lm];
          int q = qw + g * 16 + quad * 4 + r;
          int col = h * 64 + d * 16 + lm;
          Ob[((size_t)(b * S_LEN + q)) * 1024 + col] = f2bf_fast(val * linv[r]);
        }
    }
  }
}

extern "C" void kernel_launch(void* const* d_in, const int* in_sizes, int n_in,
                              void* d_out, int out_size, void* d_ws, size_t ws_size,
                              hipStream_t stream) {
  const float* X   = (const float*)d_in[0];
  const float* Wq  = (const float*)d_in[1];
  const float* Wk  = (const float*)d_in[2];
  const float* Wv  = (const float*)d_in[3];
  const float* Wo  = (const float*)d_in[4];
  const float* rel = (const float*)d_in[5];
  float* out = (float*)d_out;           // [2,2048,1024]
  float* bias_out = out + 4194304;      // [1,16,2048,2048]

  char* ws = (char*)d_ws;
  unsigned short* Xb    = (unsigned short*)(ws);
  unsigned short* WqkvT = (unsigned short*)(ws + (size_t)(8u  << 20));  // 3 x 2MB
  unsigned short* WoT   = (unsigned short*)(ws + (size_t)(14u << 20));
  unsigned short* Qb    = (unsigned short*)(ws + (size_t)(16u << 20));
  unsigned short* Kb    = (unsigned short*)(ws + (size_t)(24u << 20));
  unsigned short* Vtb   = (unsigned short*)(ws + (size_t)(32u << 20));
  unsigned short* Ob    = (unsigned short*)(ws + (size_t)(40u << 20));
  float* lut            = (float*)(ws + (size_t)(48u << 20));

  cast_x_kernel<<<4096, 256, 0, stream>>>(X, Xb, 1048576);
  dim3 tb(32, 8);
  transpose_cast3<<<dim3(32, 32, 3), tb, 0, stream>>>(Wq, Wk, Wv, WqkvT);
  transpose_cast3<<<dim3(32, 32, 1), tb, 0, stream>>>(Wo, Wo, Wo, WoT);
  build_lut_kernel<<<16, 256, 0, stream>>>(rel, lut);
  bias_out_kernel<<<65536, 256, 0, stream>>>(lut, bias_out);

  gemm_qk<<<dim3(16, 32), 256, 0, stream>>>(Xb, WqkvT, Qb, Kb);
  gemm_v<<<dim3(8, 32), 256, 0, stream>>>(Xb, WqkvT + 2 * 1048576, Vtb);
  attn_kernel<<<512, 512, 0, stream>>>(Qb, Kb, Vtb, lut, Ob);
  gemm_out<<<dim3(8, 32), 256, 0, stream>>>(Ob, WoT, out);
}

// Round 9
// 444.151 us; speedup vs baseline: 1.1698x; 1.0185x over previous
//
#include <hip/hip_runtime.h>
#include <stdint.h>

#define S_LEN 2048
#define NH 16
#define EMB 1024
#define L2E 1.44269504f

typedef __attribute__((ext_vector_type(8))) short bf16x8;
typedef __attribute__((ext_vector_type(4))) float floatx4;
typedef const __attribute__((address_space(1))) unsigned int* gas_u32p;
typedef __attribute__((address_space(3))) unsigned int* las_u32p;

static __device__ __forceinline__ void gld_lds16(const void* g, void* l) {
  __builtin_amdgcn_global_load_lds((gas_u32p)g, (las_u32p)l, 16, 0, 0);
}

static __device__ __forceinline__ unsigned short f2bf(float f) {
  unsigned int u = __float_as_uint(f);
  unsigned int r = (u + 0x7FFFu + ((u >> 16) & 1u)) >> 16;
  return (unsigned short)r;
}
static __device__ __forceinline__ unsigned short f2bf_fast(float f) {
  return (unsigned short)((__float_as_uint(f) + 0x8000u) >> 16);
}

// ---------------- fused prep: cast X, transpose 4 weights, build LUT ----------------
// blocks [0,4096): cast X (1M float4); [4096,8192): 4 weights x 1024 transpose tiles;
// [8192,8208): bias LUT.
__global__ __launch_bounds__(256) void prep_kernel(const float* __restrict__ X,
                                                   const float* __restrict__ Wq,
                                                   const float* __restrict__ Wk,
                                                   const float* __restrict__ Wv,
                                                   const float* __restrict__ Wo,
                                                   const float* __restrict__ rel,
                                                   unsigned short* __restrict__ Xb,
                                                   unsigned short* __restrict__ WT,
                                                   float* __restrict__ lut) {
  __shared__ float tile[32][33];
  const int bid = blockIdx.x, tid = threadIdx.x;
  if (bid < 4096) {
    int i = bid * 256 + tid;
    float4 v = ((const float4*)X)[i];
    ushort4 o;
    o.x = f2bf(v.x); o.y = f2bf(v.y); o.z = f2bf(v.z); o.w = f2bf(v.w);
    ((ushort4*)Xb)[i] = o;
  } else if (bid < 8192) {
    int w = (bid - 4096) >> 10, t = (bid - 4096) & 1023;
    const float* in = (w == 0) ? Wq : (w == 1) ? Wk : (w == 2) ? Wv : Wo;
    unsigned short* o = WT + (size_t)w * 1048576;
    int bx = t & 31, by = t >> 5;
    int tx = tid & 31, ty = tid >> 5;
    int x = bx * 32 + tx, y0 = by * 32 + ty;
#pragma unroll
    for (int j = 0; j < 4; j++)
      tile[ty + 8 * j][tx] = in[(y0 + 8 * j) * EMB + x];
    __syncthreads();
    int x2 = by * 32 + tx, y2 = bx * 32 + ty;
#pragma unroll
    for (int j = 0; j < 4; j++)
      o[(y2 + 8 * j) * EMB + x2] = f2bf(tile[tx][ty + 8 * j]);
  } else {
    int idx = (bid - 8192) * 256 + tid;  // 0..4095, delta = idx-2048
    int delta = idx - 2048;
    int bucket = (delta > 0) ? 16 : 0;
    int rp = (delta < 0) ? -delta : delta;
    int bl;
    if (rp < 8) bl = rp;
    else bl = 8 + (rp >= 12) + (rp >= 16) + (rp >= 23) + (rp >= 32) + (rp >= 46) + (rp >= 64) + (rp >= 91);
    bucket += bl;
#pragma unroll
    for (int h = 0; h < NH; h++)
      lut[h * 4096 + idx] = rel[bucket * NH + h];
  }
}

// ---------------- position_bias writer: [16,2048,2048] f32 (write-roofline) ----------------
__global__ void bias_out_kernel(const float* __restrict__ lut, float* __restrict__ dst) {
  int i = blockIdx.x * blockDim.x + threadIdx.x;
  int h = i >> 20;
  int rem = i & 1048575;
  int q = rem >> 9;
  int k4 = (rem & 511) << 2;
  const float* lr = lut + h * 4096 + (k4 - q + 2048);
  float4 v = make_float4(__ldg(lr), __ldg(lr + 1), __ldg(lr + 2), __ldg(lr + 3));
  ((float4*)dst)[i] = v;
}

// ---------------- fused QKV GEMM: C[4096,3072] = Xb @ WqkvT^T ----------------
// which = nBase>>10: 0 -> Q (bf16 [B,H,S,D], pre-scaled by log2e), 1 -> K, 2 -> V^T [B,H,D,S]
__global__ __launch_bounds__(256) void gemm_qkv(const unsigned short* __restrict__ A,
                                                const unsigned short* __restrict__ BT,
                                                unsigned short* __restrict__ oQ,
                                                unsigned short* __restrict__ oK,
                                                unsigned short* __restrict__ oV) {
  __shared__ __align__(16) unsigned short As[128 * 64];
  __shared__ __align__(16) unsigned short Bs[128 * 64];
  const int tid = threadIdx.x;
  const int wave = tid >> 6, lane = tid & 63;
  const int quad = lane >> 4, lm = lane & 15;
  const int wm = wave & 1, wn = wave >> 1;
  const int mBase = blockIdx.y * 128, nBase = blockIdx.x * 128;
  const int gg = (lane & 7) ^ (lane >> 3);
  const int srow = lane >> 3;
  floatx4 acc[4][4];
#pragma unroll
  for (int i = 0; i < 4; i++)
#pragma unroll
    for (int j = 0; j < 4; j++) acc[i][j] = (floatx4){0.f, 0.f, 0.f, 0.f};

  for (int kt = 0; kt < 16; kt++) {
    int k0 = kt * 64;
    __syncthreads();
#pragma unroll
    for (int c = 0; c < 4; c++) {
      int chunk = wave * 4 + c;
      int row = chunk * 8 + srow;
      gld_lds16(&A[(size_t)(mBase + row) * 1024 + k0 + gg * 8], &As[chunk * 512]);
      gld_lds16(&BT[(size_t)(nBase + row) * 1024 + k0 + gg * 8], &Bs[chunk * 512]);
    }
    __syncthreads();
#pragma unroll
    for (int hh = 0; hh < 2; hh++) {
      bf16x8 af[4], bfr[4];
#pragma unroll
      for (int i = 0; i < 4; i++)
        af[i] = *(const bf16x8*)&As[(wm * 64 + i * 16 + lm) * 64 + (((hh << 2) + quad) ^ (lm & 7)) * 8];
#pragma unroll
      for (int j = 0; j < 4; j++)
        bfr[j] = *(const bf16x8*)&Bs[(wn * 64 + j * 16 + lm) * 64 + (((hh << 2) + quad) ^ (lm & 7)) * 8];
#pragma unroll
      for (int i = 0; i < 4; i++)
#pragma unroll
        for (int j = 0; j < 4; j++)
          acc[i][j] = __builtin_amdgcn_mfma_f32_16x16x32_bf16(af[i], bfr[j], acc[i][j], 0, 0, 0);
    }
  }
  const int which = nBase >> 10;  // block-uniform
  if (which == 2) {
    // V^T epilogue: r-values are consecutive s -> pack 4 bf16 into one 8B store
#pragma unroll
    for (int i = 0; i < 4; i++)
#pragma unroll
      for (int j = 0; j < 4; j++) {
        int hd = (nBase - 2048) + wn * 64 + j * 16 + lm;
        int h = hd >> 6, d = hd & 63;
        int m = mBase + wm * 64 + i * 16 + quad * 4;
        int b = m >> 11, s = m & 2047;
        union { unsigned short u[4]; uint2 v; } pk;
#pragma unroll
        for (int r = 0; r < 4; r++) pk.u[r] = f2bf(acc[i][j][r]);
        *(uint2*)&oV[(((size_t)(b * NH + h) * 64 + d) * S_LEN) + s] = pk.v;
      }
  } else {
#pragma unroll
    for (int i = 0; i < 4; i++)
#pragma unroll
      for (int j = 0; j < 4; j++)
#pragma unroll
        for (int r = 0; r < 4; r++) {
          int row = mBase + wm * 64 + i * 16 + quad * 4 + r;
          int col = nBase + wn * 64 + j * 16 + lm;
          int b = row >> 11, s = row & 2047;
          int cw = col & 1023;
          int h = cw >> 6, d = cw & 63;
          float v = acc[i][j][r];
          if (which == 0) v *= L2E;  // pre-scale Q for exp2-based softmax
          unsigned short sv = f2bf(v);
          if (which == 0) oQ[(((size_t)(b * NH + h) * S_LEN + s) * 64) + d] = sv;
          else            oK[(((size_t)(b * NH + h) * S_LEN + s) * 64) + d] = sv;
        }
  }
}

// ---------------- GEMM out-proj: f32 [M,1024] ----------------
__global__ __launch_bounds__(256) void gemm_out(const unsigned short* __restrict__ A,
                                                const unsigned short* __restrict__ BT,
                                                float* __restrict__ oF) {
  __shared__ __align__(16) unsigned short As[128 * 64];
  __shared__ __align__(16) unsigned short Bs[128 * 64];
  const int tid = threadIdx.x;
  const int wave = tid >> 6, lane = tid & 63;
  const int quad = lane >> 4, lm = lane & 15;
  const int wm = wave & 1, wn = wave >> 1;
  const int mBase = blockIdx.y * 128, nBase = blockIdx.x * 128;
  const int gg = (lane & 7) ^ (lane >> 3);
  const int srow = lane >> 3;
  floatx4 acc[4][4];
#pragma unroll
  for (int i = 0; i < 4; i++)
#pragma unroll
    for (int j = 0; j < 4; j++) acc[i][j] = (floatx4){0.f, 0.f, 0.f, 0.f};

  for (int kt = 0; kt < 16; kt++) {
    int k0 = kt * 64;
    __syncthreads();
#pragma unroll
    for (int c = 0; c < 4; c++) {
      int chunk = wave * 4 + c;
      int row = chunk * 8 + srow;
      gld_lds16(&A[(size_t)(mBase + row) * 1024 + k0 + gg * 8], &As[chunk * 512]);
      gld_lds16(&BT[(size_t)(nBase + row) * 1024 + k0 + gg * 8], &Bs[chunk * 512]);
    }
    __syncthreads();
#pragma unroll
    for (int hh = 0; hh < 2; hh++) {
      bf16x8 af[4], bfr[4];
#pragma unroll
      for (int i = 0; i < 4; i++)
        af[i] = *(const bf16x8*)&As[(wm * 64 + i * 16 + lm) * 64 + (((hh << 2) + quad) ^ (lm & 7)) * 8];
#pragma unroll
      for (int j = 0; j < 4; j++)
        bfr[j] = *(const bf16x8*)&Bs[(wn * 64 + j * 16 + lm) * 64 + (((hh << 2) + quad) ^ (lm & 7)) * 8];
#pragma unroll
      for (int i = 0; i < 4; i++)
#pragma unroll
        for (int j = 0; j < 4; j++)
          acc[i][j] = __builtin_amdgcn_mfma_f32_16x16x32_bf16(af[i], bfr[j], acc[i][j], 0, 0, 0);
    }
  }
#pragma unroll
  for (int i = 0; i < 4; i++)
#pragma unroll
    for (int j = 0; j < 4; j++)
#pragma unroll
      for (int r = 0; r < 4; r++) {
        int row = mBase + wm * 64 + i * 16 + quad * 4 + r;
        int col = nBase + wn * 64 + j * 16 + lm;
        oF[(size_t)row * 1024 + col] = acc[i][j][r];
      }
}

// ---------------- flash attention, 8 waves, in-block split-K, exp2 softmax ----------------
// grid 512 (XCD swizzle). Block = (bh, 128-q tile). Waves 0-3: k in [0,1024); waves 4-7: [1024,2048).
// Q pre-scaled by log2e; LUT window + far constants scaled here; exp via native v_exp_f32.
__global__ __launch_bounds__(512, 4) void attn_kernel(const unsigned short* __restrict__ Qb,
                                                      const unsigned short* __restrict__ Kb,
                                                      const unsigned short* __restrict__ Vtb,
                                                      const float* __restrict__ lut,
                                                      unsigned short* __restrict__ Ob) {
  __shared__ __align__(16) unsigned short Kl[2][64 * 64];
  __shared__ __align__(16) unsigned short Vl[2][64 * 64];
  __shared__ __align__(16) unsigned short Pl[8][16 * 72];
  __shared__ float lutS[512];
  const int tid = threadIdx.x;
  const int wave = tid >> 6, lane = tid & 63;
  const int quad = lane >> 4, lm = lane & 15;
  const int ws = wave & 3, half = wave >> 2;
  const int ii = blockIdx.x;
  const int bh = (ii & 7) * 4 + ((ii >> 3) & 3);
  const int qTile = (ii >> 5) * 128;
  const int b = bh >> 4, h = bh & 15;
  const unsigned short* Qp = Qb + (size_t)bh * S_LEN * 64;
  const unsigned short* Kp = Kb + (size_t)bh * S_LEN * 64;
  const unsigned short* Vp = Vtb + (size_t)bh * 64 * S_LEN;
  const float* lrow = lut + h * 4096;
  const float cneg = lrow[0] * L2E, cpos = lrow[4095] * L2E;
  const int gg = (lane & 7) ^ (lane >> 3);
  const int srow = lane >> 3;
  const int qw = qTile + ws * 32;

  lutS[tid & 511] = lrow[2048 - 256 + (tid & 511)] * L2E;  // deltas [-256, 255]

  bf16x8 aq[2][2];
#pragma unroll
  for (int g = 0; g < 2; g++)
#pragma unroll
    for (int hh = 0; hh < 2; hh++)
      aq[g][hh] = *(const bf16x8*)&Qp[(qw + g * 16 + lm) * 64 + hh * 32 + quad * 8];

  floatx4 accO[2][4];
#pragma unroll
  for (int g = 0; g < 2; g++)
#pragma unroll
    for (int d = 0; d < 4; d++) accO[g][d] = (floatx4){0.f, 0.f, 0.f, 0.f};
  float lp[2] = {0.f, 0.f};

  unsigned short* Pw = Pl[wave];

  for (int ktl = 0; ktl < 16; ktl++) {
    const int kBase = (half << 10) + ktl * 64;
    __syncthreads();
#pragma unroll
    for (int c = 0; c < 2; c++) {
      int chunk = ws * 2 + c;
      int row = chunk * 8 + srow;
      gld_lds16(&Kp[(size_t)(kBase + row) * 64 + gg * 8], &Kl[half][chunk * 512]);
      gld_lds16(&Vp[(size_t)row * S_LEN + kBase + gg * 8], &Vl[half][chunk * 512]);
    }
    __syncthreads();

    const bool farTile = (kBase + 154 <= qTile) || (kBase >= qTile + 218);
    const float cfar = (kBase < qTile) ? cneg : cpos;

    // S^T = K·Q^T : thread holds q=lm, k=nt*16+quad*4+r
    floatx4 s4[2][4];
#pragma unroll
    for (int nt = 0; nt < 4; nt++) {
      int rbase = (nt * 16 + lm) * 64;
      bf16x8 kf0 = *(const bf16x8*)&Kl[half][rbase + ((quad ^ (lm & 7)) << 3)];
      bf16x8 kf1 = *(const bf16x8*)&Kl[half][rbase + (((4 + quad) ^ (lm & 7)) << 3)];
#pragma unroll
      for (int g = 0; g < 2; g++) {
        floatx4 z = (floatx4){0.f, 0.f, 0.f, 0.f};
        z = __builtin_amdgcn_mfma_f32_16x16x32_bf16(kf0, aq[g][0], z, 0, 0, 0);
        z = __builtin_amdgcn_mfma_f32_16x16x32_bf16(kf1, aq[g][1], z, 0, 0, 0);
        s4[g][nt] = z;
      }
    }

    bf16x8 pa[2][2];
#pragma unroll
    for (int g = 0; g < 2; g++) {
      const int b0 = kBase + quad * 4 - (qw + g * 16 + lm) + 256;
      float psum = 0.f;
#pragma unroll
      for (int nt = 0; nt < 4; nt++) {
        union { unsigned short u[4]; uint2 v; } pk;
#pragma unroll
        for (int r = 0; r < 4; r++) {
          float sv;
          if (farTile) sv = s4[g][nt][r] + cfar;
          else         sv = s4[g][nt][r] + lutS[b0 + nt * 16 + r];
          float p = __builtin_amdgcn_exp2f(sv);
          psum += p;
          pk.u[r] = f2bf_fast(p);
        }
        *(uint2*)&Pw[lm * 72 + nt * 16 + quad * 4] = pk.v;  // P[q=lm][k..k+3]
      }
      lp[g] += psum;
      pa[g][0] = *(const bf16x8*)&Pw[lm * 72 + quad * 8];
      pa[g][1] = *(const bf16x8*)&Pw[lm * 72 + 32 + quad * 8];
    }

#pragma unroll
    for (int d = 0; d < 4; d++) {
      int rbase = (d * 16 + lm) * 64;
      bf16x8 vf0 = *(const bf16x8*)&Vl[half][rbase + ((quad ^ (lm & 7)) << 3)];
      bf16x8 vf1 = *(const bf16x8*)&Vl[half][rbase + (((4 + quad) ^ (lm & 7)) << 3)];
      accO[0][d] = __builtin_amdgcn_mfma_f32_16x16x32_bf16(pa[0][0], vf0, accO[0][d], 0, 0, 0);
      accO[0][d] = __builtin_amdgcn_mfma_f32_16x16x32_bf16(pa[0][1], vf1, accO[0][d], 0, 0, 0);
      accO[1][d] = __builtin_amdgcn_mfma_f32_16x16x32_bf16(pa[1][0], vf0, accO[1][d], 0, 0, 0);
      accO[1][d] = __builtin_amdgcn_mfma_f32_16x16x32_bf16(pa[1][1], vf1, accO[1][d], 0, 0, 0);
    }
  }

#pragma unroll
  for (int g = 0; g < 2; g++) {
    lp[g] += __shfl_xor(lp[g], 16, 64);
    lp[g] += __shfl_xor(lp[g], 32, 64);
  }

  __syncthreads();  // all k-loop LDS reads done; alias Kl/Vl as f32 exchange buffers
  float* Ox = (ws < 2) ? ((float*)&Kl[0][0]) + ws * 2048 : ((float*)&Vl[0][0]) + (ws - 2) * 2048;
  float* lpf = (float*)&Pl[0][0];
  if (half == 1) {
#pragma unroll
    for (int g = 0; g < 2; g++) {
#pragma unroll
      for (int d = 0; d < 4; d++)
#pragma unroll
        for (int r = 0; r < 4; r++)
          Ox[(g * 16 + quad * 4 + r) * 64 + d * 16 + lm] = accO[g][d][r];
      if (quad == 0) lpf[ws * 32 + g * 16 + lm] = lp[g];
    }
  }
  __syncthreads();
  if (half == 0) {
    float ltot[2];
#pragma unroll
    for (int g = 0; g < 2; g++) ltot[g] = lp[g] + lpf[ws * 32 + g * 16 + lm];
#pragma unroll
    for (int g = 0; g < 2; g++) {
      float linv[4];
#pragma unroll
      for (int r = 0; r < 4; r++) linv[r] = 1.f / __shfl(ltot[g], quad * 4 + r, 64);
#pragma unroll
      for (int d = 0; d < 4; d++)
#pragma unroll
        for (int r = 0; r < 4; r++) {
          float val = accO[g][d][r] + Ox[(g * 16 + quad * 4 + r) * 64 + d * 16 + lm];
          int q = qw + g * 16 + quad * 4 + r;
          int col = h * 64 + d * 16 + lm;
          Ob[((size_t)(b * S_LEN + q)) * 1024 + col] = f2bf_fast(val * linv[r]);
        }
    }
  }
}

extern "C" void kernel_launch(void* const* d_in, const int* in_sizes, int n_in,
                              void* d_out, int out_size, void* d_ws, size_t ws_size,
                              hipStream_t stream) {
  const float* X   = (const float*)d_in[0];
  const float* Wq  = (const float*)d_in[1];
  const float* Wk  = (const float*)d_in[2];
  const float* Wv  = (const float*)d_in[3];
  const float* Wo  = (const float*)d_in[4];
  const float* rel = (const float*)d_in[5];
  float* out = (float*)d_out;           // [2,2048,1024]
  float* bias_out = out + 4194304;      // [1,16,2048,2048]

  char* ws = (char*)d_ws;
  unsigned short* Xb  = (unsigned short*)(ws);
  unsigned short* WT  = (unsigned short*)(ws + (size_t)(8u << 20));   // Wq|Wk|Wv|Wo transposed, 4 x 2MB
  unsigned short* Qb  = (unsigned short*)(ws + (size_t)(16u << 20));
  unsigned short* Kb  = (unsigned short*)(ws + (size_t)(24u << 20));
  unsigned short* Vtb = (unsigned short*)(ws + (size_t)(32u << 20));
  unsigned short* Ob  = (unsigned short*)(ws + (size_t)(40u << 20));
  float* lut          = (float*)(ws + (size_t)(48u << 20));

  prep_kernel<<<8208, 256, 0, stream>>>(X, Wq, Wk, Wv, Wo, rel, Xb, WT, lut);
  bias_out_kernel<<<65536, 256, 0, stream>>>(lut, bias_out);
  gemm_qkv<<<dim3(24, 32), 256, 0, stream>>>(Xb, WT, Qb, Kb, Vtb);
  attn_kernel<<<512, 512, 0, stream>>>(Qb, Kb, Vtb, lut, Ob);
  gemm_out<<<dim3(8, 32), 256, 0, stream>>>(Ob, WT + 3 * 1048576, out);
}

// Round 10
// 443.201 us; speedup vs baseline: 1.1723x; 1.0021x over previous
//
#include <hip/hip_runtime.h>
#include <stdint.h>

#define S_LEN 2048
#define NH 16
#define EMB 1024
#define L2E 1.44269504f

typedef __attribute__((ext_vector_type(8))) short bf16x8;
typedef __attribute__((ext_vector_type(4))) float floatx4;
typedef const __attribute__((address_space(1))) unsigned int* gas_u32p;
typedef __attribute__((address_space(3))) unsigned int* las_u32p;

static __device__ __forceinline__ void gld_lds16(const void* g, void* l) {
  __builtin_amdgcn_global_load_lds((gas_u32p)g, (las_u32p)l, 16, 0, 0);
}

static __device__ __forceinline__ unsigned short f2bf(float f) {
  unsigned int u = __float_as_uint(f);
  unsigned int r = (u + 0x7FFFu + ((u >> 16) & 1u)) >> 16;
  return (unsigned short)r;
}
static __device__ __forceinline__ unsigned short f2bf_fast(float f) {
  return (unsigned short)((__float_as_uint(f) + 0x8000u) >> 16);
}

// ---------------- fused prep: cast X, transpose 4 weights, build LUT ----------------
__global__ __launch_bounds__(256) void prep_kernel(const float* __restrict__ X,
                                                   const float* __restrict__ Wq,
                                                   const float* __restrict__ Wk,
                                                   const float* __restrict__ Wv,
                                                   const float* __restrict__ Wo,
                                                   const float* __restrict__ rel,
                                                   unsigned short* __restrict__ Xb,
                                                   unsigned short* __restrict__ WT,
                                                   float* __restrict__ lut) {
  __shared__ float tile[32][33];
  const int bid = blockIdx.x, tid = threadIdx.x;
  if (bid < 4096) {
    int i = bid * 256 + tid;
    float4 v = ((const float4*)X)[i];
    ushort4 o;
    o.x = f2bf(v.x); o.y = f2bf(v.y); o.z = f2bf(v.z); o.w = f2bf(v.w);
    ((ushort4*)Xb)[i] = o;
  } else if (bid < 8192) {
    int w = (bid - 4096) >> 10, t = (bid - 4096) & 1023;
    const float* in = (w == 0) ? Wq : (w == 1) ? Wk : (w == 2) ? Wv : Wo;
    unsigned short* o = WT + (size_t)w * 1048576;
    int bx = t & 31, by = t >> 5;
    int tx = tid & 31, ty = tid >> 5;
    int x = bx * 32 + tx, y0 = by * 32 + ty;
#pragma unroll
    for (int j = 0; j < 4; j++)
      tile[ty + 8 * j][tx] = in[(y0 + 8 * j) * EMB + x];
    __syncthreads();
    int x2 = by * 32 + tx, y2 = bx * 32 + ty;
#pragma unroll
    for (int j = 0; j < 4; j++)
      o[(y2 + 8 * j) * EMB + x2] = f2bf(tile[tx][ty + 8 * j]);
  } else {
    int idx = (bid - 8192) * 256 + tid;
    int delta = idx - 2048;
    int bucket = (delta > 0) ? 16 : 0;
    int rp = (delta < 0) ? -delta : delta;
    int bl;
    if (rp < 8) bl = rp;
    else bl = 8 + (rp >= 12) + (rp >= 16) + (rp >= 23) + (rp >= 32) + (rp >= 46) + (rp >= 64) + (rp >= 91);
    bucket += bl;
#pragma unroll
    for (int h = 0; h < NH; h++)
      lut[h * 4096 + idx] = rel[bucket * NH + h];
  }
}

// ---------------- position_bias writer: [16,2048,2048] f32 (write-roofline) ----------------
__global__ void bias_out_kernel(const float* __restrict__ lut, float* __restrict__ dst) {
  int i = blockIdx.x * blockDim.x + threadIdx.x;
  int h = i >> 20;
  int rem = i & 1048575;
  int q = rem >> 9;
  int k4 = (rem & 511) << 2;
  const float* lr = lut + h * 4096 + (k4 - q + 2048);
  float4 v = make_float4(__ldg(lr), __ldg(lr + 1), __ldg(lr + 2), __ldg(lr + 3));
  ((float4*)dst)[i] = v;
}

// ---------------- fused QKV GEMM: C[4096,3072] = Xb @ WqkvT^T ----------------
__global__ __launch_bounds__(256) void gemm_qkv(const unsigned short* __restrict__ A,
                                                const unsigned short* __restrict__ BT,
                                                unsigned short* __restrict__ oQ,
                                                unsigned short* __restrict__ oK,
                                                unsigned short* __restrict__ oV) {
  __shared__ __align__(16) unsigned short As[128 * 64];
  __shared__ __align__(16) unsigned short Bs[128 * 64];
  const int tid = threadIdx.x;
  const int wave = tid >> 6, lane = tid & 63;
  const int quad = lane >> 4, lm = lane & 15;
  const int wm = wave & 1, wn = wave >> 1;
  const int mBase = blockIdx.y * 128, nBase = blockIdx.x * 128;
  const int gg = (lane & 7) ^ (lane >> 3);
  const int srow = lane >> 3;
  floatx4 acc[4][4];
#pragma unroll
  for (int i = 0; i < 4; i++)
#pragma unroll
    for (int j = 0; j < 4; j++) acc[i][j] = (floatx4){0.f, 0.f, 0.f, 0.f};

  for (int kt = 0; kt < 16; kt++) {
    int k0 = kt * 64;
    __syncthreads();
#pragma unroll
    for (int c = 0; c < 4; c++) {
      int chunk = wave * 4 + c;
      int row = chunk * 8 + srow;
      gld_lds16(&A[(size_t)(mBase + row) * 1024 + k0 + gg * 8], &As[chunk * 512]);
      gld_lds16(&BT[(size_t)(nBase + row) * 1024 + k0 + gg * 8], &Bs[chunk * 512]);
    }
    __syncthreads();
#pragma unroll
    for (int hh = 0; hh < 2; hh++) {
      bf16x8 af[4], bfr[4];
#pragma unroll
      for (int i = 0; i < 4; i++)
        af[i] = *(const bf16x8*)&As[(wm * 64 + i * 16 + lm) * 64 + (((hh << 2) + quad) ^ (lm & 7)) * 8];
#pragma unroll
      for (int j = 0; j < 4; j++)
        bfr[j] = *(const bf16x8*)&Bs[(wn * 64 + j * 16 + lm) * 64 + (((hh << 2) + quad) ^ (lm & 7)) * 8];
#pragma unroll
      for (int i = 0; i < 4; i++)
#pragma unroll
        for (int j = 0; j < 4; j++)
          acc[i][j] = __builtin_amdgcn_mfma_f32_16x16x32_bf16(af[i], bfr[j], acc[i][j], 0, 0, 0);
    }
  }
  const int which = nBase >> 10;  // block-uniform
  if (which == 2) {
#pragma unroll
    for (int i = 0; i < 4; i++)
#pragma unroll
      for (int j = 0; j < 4; j++) {
        int hd = (nBase - 2048) + wn * 64 + j * 16 + lm;
        int h = hd >> 6, d = hd & 63;
        int m = mBase + wm * 64 + i * 16 + quad * 4;
        int b = m >> 11, s = m & 2047;
        union { unsigned short u[4]; uint2 v; } pk;
#pragma unroll
        for (int r = 0; r < 4; r++) pk.u[r] = f2bf(acc[i][j][r]);
        *(uint2*)&oV[(((size_t)(b * NH + h) * 64 + d) * S_LEN) + s] = pk.v;
      }
  } else {
#pragma unroll
    for (int i = 0; i < 4; i++)
#pragma unroll
      for (int j = 0; j < 4; j++)
#pragma unroll
        for (int r = 0; r < 4; r++) {
          int row = mBase + wm * 64 + i * 16 + quad * 4 + r;
          int col = nBase + wn * 64 + j * 16 + lm;
          int b = row >> 11, s = row & 2047;
          int cw = col & 1023;
          int h = cw >> 6, d = cw & 63;
          float v = acc[i][j][r];
          if (which == 0) v *= L2E;  // pre-scale Q for exp2-based softmax
          unsigned short sv = f2bf(v);
          if (which == 0) oQ[(((size_t)(b * NH + h) * S_LEN + s) * 64) + d] = sv;
          else            oK[(((size_t)(b * NH + h) * S_LEN + s) * 64) + d] = sv;
        }
  }
}

// ---------------- GEMM out-proj: f32 [M,1024] ----------------
__global__ __launch_bounds__(256) void gemm_out(const unsigned short* __restrict__ A,
                                                const unsigned short* __restrict__ BT,
                                                float* __restrict__ oF) {
  __shared__ __align__(16) unsigned short As[128 * 64];
  __shared__ __align__(16) unsigned short Bs[128 * 64];
  const int tid = threadIdx.x;
  const int wave = tid >> 6, lane = tid & 63;
  const int quad = lane >> 4, lm = lane & 15;
  const int wm = wave & 1, wn = wave >> 1;
  const int mBase = blockIdx.y * 128, nBase = blockIdx.x * 128;
  const int gg = (lane & 7) ^ (lane >> 3);
  const int srow = lane >> 3;
  floatx4 acc[4][4];
#pragma unroll
  for (int i = 0; i < 4; i++)
#pragma unroll
    for (int j = 0; j < 4; j++) acc[i][j] = (floatx4){0.f, 0.f, 0.f, 0.f};

  for (int kt = 0; kt < 16; kt++) {
    int k0 = kt * 64;
    __syncthreads();
#pragma unroll
    for (int c = 0; c < 4; c++) {
      int chunk = wave * 4 + c;
      int row = chunk * 8 + srow;
      gld_lds16(&A[(size_t)(mBase + row) * 1024 + k0 + gg * 8], &As[chunk * 512]);
      gld_lds16(&BT[(size_t)(nBase + row) * 1024 + k0 + gg * 8], &Bs[chunk * 512]);
    }
    __syncthreads();
#pragma unroll
    for (int hh = 0; hh < 2; hh++) {
      bf16x8 af[4], bfr[4];
#pragma unroll
      for (int i = 0; i < 4; i++)
        af[i] = *(const bf16x8*)&As[(wm * 64 + i * 16 + lm) * 64 + (((hh << 2) + quad) ^ (lm & 7)) * 8];
#pragma unroll
      for (int j = 0; j < 4; j++)
        bfr[j] = *(const bf16x8*)&Bs[(wn * 64 + j * 16 + lm) * 64 + (((hh << 2) + quad) ^ (lm & 7)) * 8];
#pragma unroll
      for (int i = 0; i < 4; i++)
#pragma unroll
        for (int j = 0; j < 4; j++)
          acc[i][j] = __builtin_amdgcn_mfma_f32_16x16x32_bf16(af[i], bfr[j], acc[i][j], 0, 0, 0);
    }
  }
#pragma unroll
  for (int i = 0; i < 4; i++)
#pragma unroll
    for (int j = 0; j < 4; j++)
#pragma unroll
      for (int r = 0; r < 4; r++) {
        int row = mBase + wm * 64 + i * 16 + quad * 4 + r;
        int col = nBase + wn * 64 + j * 16 + lm;
        oF[(size_t)row * 1024 + col] = acc[i][j][r];
      }
}

// ---------------- flash attention: single-barrier double-buffered K-loop ----------------
// grid 512 (XCD swizzle), 8 waves. Waves 0-3: k half 0, waves 4-7: k half 1.
// K-tile = 32; two LDS buffers per half; loop = {barrier; stage(t+1)->alt; compute(t)}.
// The vmcnt(0) at each barrier drains a load issued one full compute phase earlier -> ~no stall.
__global__ __launch_bounds__(512, 4) void attn_kernel(const unsigned short* __restrict__ Qb,
                                                      const unsigned short* __restrict__ Kb,
                                                      const unsigned short* __restrict__ Vtb,
                                                      const float* __restrict__ lut,
                                                      unsigned short* __restrict__ Ob) {
  __shared__ __align__(16) unsigned short Kl[2][2][2048];  // [half][buf][32 k x 64 d]
  __shared__ __align__(16) unsigned short Vl[2][2][2048];  // [half][buf][64 d x 32 k]
  __shared__ __align__(16) unsigned short Pl[8][16 * 40];  // P: 16 q x 32 k, stride 40
  __shared__ float lutS[512];
  const int tid = threadIdx.x;
  const int wave = tid >> 6, lane = tid & 63;
  const int quad = lane >> 4, lm = lane & 15;
  const int ws = wave & 3, half = wave >> 2;
  const int ii = blockIdx.x;
  const int bh = (ii & 7) * 4 + ((ii >> 3) & 3);
  const int qTile = (ii >> 5) * 128;
  const int b = bh >> 4, h = bh & 15;
  const unsigned short* Qp = Qb + (size_t)bh * S_LEN * 64;
  const unsigned short* Kp = Kb + (size_t)bh * S_LEN * 64;
  const unsigned short* Vp = Vtb + (size_t)bh * 64 * S_LEN;
  const float* lrow = lut + h * 4096;
  const float cneg = lrow[0] * L2E, cpos = lrow[4095] * L2E;
  const int srow = lane >> 3;                    // K staging row-in-chunk
  const int gg = (lane & 7) ^ (srow & 7);        // K granule swizzle
  const int vrow = lane >> 2;                    // V staging row-in-chunk (0..15)
  const int vgg = (lane & 3) ^ ((lane >> 3) & 3);// V granule swizzle
  const int qw = qTile + ws * 32;

  lutS[tid & 511] = lrow[2048 - 256 + (tid & 511)] * L2E;  // deltas [-256, 255]

  bf16x8 aq[2][2];
#pragma unroll
  for (int g = 0; g < 2; g++)
#pragma unroll
    for (int hh = 0; hh < 2; hh++)
      aq[g][hh] = *(const bf16x8*)&Qp[(qw + g * 16 + lm) * 64 + hh * 32 + quad * 8];

  floatx4 accO[2][4];
#pragma unroll
  for (int g = 0; g < 2; g++)
#pragma unroll
    for (int d = 0; d < 4; d++) accO[g][d] = (floatx4){0.f, 0.f, 0.f, 0.f};
  float lp[2] = {0.f, 0.f};

  unsigned short* Pw = Pl[wave];
  const int vswz = ((lm >> 1) & 3);  // V read granule swizzle component

  // prologue: stage tile 0 into buf 0
  {
    const int kBase = half << 10;
    gld_lds16(&Kp[(size_t)(kBase + ws * 8 + srow) * 64 + gg * 8], &Kl[half][0][ws * 512]);
    gld_lds16(&Vp[(size_t)(ws * 16 + vrow) * S_LEN + kBase + vgg * 8], &Vl[half][0][ws * 512]);
  }

  for (int ktl = 0; ktl < 32; ktl++) {
    const int buf = ktl & 1;
    const int kBase = (half << 10) + ktl * 32;
    __syncthreads();  // implicit vmcnt(0): stage(ktl) landed; prev-iter LDS reads done
    if (ktl < 31) {
      const int kn = kBase + 32;
      gld_lds16(&Kp[(size_t)(kn + ws * 8 + srow) * 64 + gg * 8], &Kl[half][buf ^ 1][ws * 512]);
      gld_lds16(&Vp[(size_t)(ws * 16 + vrow) * S_LEN + kn + vgg * 8], &Vl[half][buf ^ 1][ws * 512]);
    }
    const unsigned short* Kbuf = Kl[half][buf];
    const unsigned short* Vbuf = Vl[half][buf];

    const bool farTile = (kBase + 122 <= qTile) || (kBase >= qTile + 218);
    const float cfar = (kBase < qTile) ? cneg : cpos;

    // S^T = K·Q^T : thread holds q=lm, k = nt*16 + quad*4 + r (nt in 0..1)
    floatx4 s4[2][2];
#pragma unroll
    for (int nt = 0; nt < 2; nt++) {
      int rbase = (nt * 16 + lm) * 64;
      bf16x8 kf0 = *(const bf16x8*)&Kbuf[rbase + ((quad ^ (lm & 7)) << 3)];
      bf16x8 kf1 = *(const bf16x8*)&Kbuf[rbase + (((4 + quad) ^ (lm & 7)) << 3)];
#pragma unroll
      for (int g = 0; g < 2; g++) {
        floatx4 z = (floatx4){0.f, 0.f, 0.f, 0.f};
        z = __builtin_amdgcn_mfma_f32_16x16x32_bf16(kf0, aq[g][0], z, 0, 0, 0);
        z = __builtin_amdgcn_mfma_f32_16x16x32_bf16(kf1, aq[g][1], z, 0, 0, 0);
        s4[g][nt] = z;
      }
    }

    bf16x8 pa[2];
#pragma unroll
    for (int g = 0; g < 2; g++) {
      const int b0 = kBase + quad * 4 - (qw + g * 16 + lm) + 256;
      float psum = 0.f;
#pragma unroll
      for (int nt = 0; nt < 2; nt++) {
        union { unsigned short u[4]; uint2 v; } pk;
#pragma unroll
        for (int r = 0; r < 4; r++) {
          float sv;
          if (farTile) sv = s4[g][nt][r] + cfar;
          else         sv = s4[g][nt][r] + lutS[b0 + nt * 16 + r];
          float p = __builtin_amdgcn_exp2f(sv);
          psum += p;
          pk.u[r] = f2bf_fast(p);
        }
        *(uint2*)&Pw[lm * 40 + nt * 16 + quad * 4] = pk.v;  // P[q=lm][k..k+3]
      }
      lp[g] += psum;
      // same-wave DS ordering: this read sees the writes above
      pa[g] = *(const bf16x8*)&Pw[lm * 40 + quad * 8];
    }

#pragma unroll
    for (int d = 0; d < 4; d++) {
      bf16x8 vf = *(const bf16x8*)&Vbuf[(d * 16 + lm) * 32 + ((quad ^ vswz) << 3)];
      accO[0][d] = __builtin_amdgcn_mfma_f32_16x16x32_bf16(pa[0], vf, accO[0][d], 0, 0, 0);
      accO[1][d] = __builtin_amdgcn_mfma_f32_16x16x32_bf16(pa[1], vf, accO[1][d], 0, 0, 0);
    }
  }

  // reduce row-sums across quads (within wave)
#pragma unroll
  for (int g = 0; g < 2; g++) {
    lp[g] += __shfl_xor(lp[g], 16, 64);
    lp[g] += __shfl_xor(lp[g], 32, 64);
  }

  __syncthreads();  // all k-loop LDS reads done; alias Kl/Vl as f32 exchange buffers
  float* Ox = (ws < 2) ? ((float*)&Kl[0][0][0]) + ws * 2048 : ((float*)&Vl[0][0][0]) + (ws - 2) * 2048;
  float* lpf = (float*)&Pl[0][0];
  if (half == 1) {
#pragma unroll
    for (int g = 0; g < 2; g++) {
#pragma unroll
      for (int d = 0; d < 4; d++)
#pragma unroll
        for (int r = 0; r < 4; r++)
          Ox[(g * 16 + quad * 4 + r) * 64 + d * 16 + lm] = accO[g][d][r];
      if (quad == 0) lpf[ws * 32 + g * 16 + lm] = lp[g];
    }
  }
  __syncthreads();
  if (half == 0) {
    float ltot[2];
#pragma unroll
    for (int g = 0; g < 2; g++) ltot[g] = lp[g] + lpf[ws * 32 + g * 16 + lm];
#pragma unroll
    for (int g = 0; g < 2; g++) {
      float linv[4];
#pragma unroll
      for (int r = 0; r < 4; r++) linv[r] = 1.f / __shfl(ltot[g], quad * 4 + r, 64);
#pragma unroll
      for (int d = 0; d < 4; d++)
#pragma unroll
        for (int r = 0; r < 4; r++) {
          float val = accO[g][d][r] + Ox[(g * 16 + quad * 4 + r) * 64 + d * 16 + lm];
          int q = qw + g * 16 + quad * 4 + r;
          int col = h * 64 + d * 16 + lm;
          Ob[((size_t)(b * S_LEN + q)) * 1024 + col] = f2bf_fast(val * linv[r]);
        }
    }
  }
}

extern "C" void kernel_launch(void* const* d_in, const int* in_sizes, int n_in,
                              void* d_out, int out_size, void* d_ws, size_t ws_size,
                              hipStream_t stream) {
  const float* X   = (const float*)d_in[0];
  const float* Wq  = (const float*)d_in[1];
  const float* Wk  = (const float*)d_in[2];
  const float* Wv  = (const float*)d_in[3];
  const float* Wo  = (const float*)d_in[4];
  const float* rel = (const float*)d_in[5];
  float* out = (float*)d_out;           // [2,2048,1024]
  float* bias_out = out + 4194304;      // [1,16,2048,2048]

  char* ws = (char*)d_ws;
  unsigned short* Xb  = (unsigned short*)(ws);
  unsigned short* WT  = (unsigned short*)(ws + (size_t)(8u << 20));   // Wq|Wk|Wv|Wo transposed
  unsigned short* Qb  = (unsigned short*)(ws + (size_t)(16u << 20));
  unsigned short* Kb  = (unsigned short*)(ws + (size_t)(24u << 20));
  unsigned short* Vtb = (unsigned short*)(ws + (size_t)(32u << 20));
  unsigned short* Ob  = (unsigned short*)(ws + (size_t)(40u << 20));
  float* lut          = (float*)(ws + (size_t)(48u << 20));

  prep_kernel<<<8208, 256, 0, stream>>>(X, Wq, Wk, Wv, Wo, rel, Xb, WT, lut);
  bias_out_kernel<<<65536, 256, 0, stream>>>(lut, bias_out);
  gemm_qkv<<<dim3(24, 32), 256, 0, stream>>>(Xb, WT, Qb, Kb, Vtb);
  attn_kernel<<<512, 512, 0, stream>>>(Qb, Kb, Vtb, lut, Ob);
  gemm_out<<<dim3(8, 32), 256, 0, stream>>>(Ob, WT + 3 * 1048576, out);
}

// Round 11
// 418.105 us; speedup vs baseline: 1.2426x; 1.0600x over previous
//
#include <hip/hip_runtime.h>
#include <stdint.h>

#define S_LEN 2048
#define NH 16
#define EMB 1024
#define L2E 1.44269504f

typedef __attribute__((ext_vector_type(8))) short bf16x8;
typedef __attribute__((ext_vector_type(4))) float floatx4;
typedef const __attribute__((address_space(1))) unsigned int* gas_u32p;
typedef __attribute__((address_space(3))) unsigned int* las_u32p;

static __device__ __forceinline__ void gld_lds16(const void* g, void* l) {
  __builtin_amdgcn_global_load_lds((gas_u32p)g, (las_u32p)l, 16, 0, 0);
}

static __device__ __forceinline__ unsigned short f2bf(float f) {
  unsigned int u = __float_as_uint(f);
  unsigned int r = (u + 0x7FFFu + ((u >> 16) & 1u)) >> 16;
  return (unsigned short)r;
}
static __device__ __forceinline__ unsigned short f2bf_fast(float f) {
  return (unsigned short)((__float_as_uint(f) + 0x8000u) >> 16);
}

// ---------------- fused prep: cast X, transpose 4 weights, build LUT ----------------
__global__ __launch_bounds__(256) void prep_kernel(const float* __restrict__ X,
                                                   const float* __restrict__ Wq,
                                                   const float* __restrict__ Wk,
                                                   const float* __restrict__ Wv,
                                                   const float* __restrict__ Wo,
                                                   const float* __restrict__ rel,
                                                   unsigned short* __restrict__ Xb,
                                                   unsigned short* __restrict__ WT,
                                                   float* __restrict__ lut) {
  __shared__ float tile[32][33];
  const int bid = blockIdx.x, tid = threadIdx.x;
  if (bid < 4096) {
    int i = bid * 256 + tid;
    float4 v = ((const float4*)X)[i];
    ushort4 o;
    o.x = f2bf(v.x); o.y = f2bf(v.y); o.z = f2bf(v.z); o.w = f2bf(v.w);
    ((ushort4*)Xb)[i] = o;
  } else if (bid < 8192) {
    int w = (bid - 4096) >> 10, t = (bid - 4096) & 1023;
    const float* in = (w == 0) ? Wq : (w == 1) ? Wk : (w == 2) ? Wv : Wo;
    unsigned short* o = WT + (size_t)w * 1048576;
    int bx = t & 31, by = t >> 5;
    int tx = tid & 31, ty = tid >> 5;
    int x = bx * 32 + tx, y0 = by * 32 + ty;
#pragma unroll
    for (int j = 0; j < 4; j++)
      tile[ty + 8 * j][tx] = in[(y0 + 8 * j) * EMB + x];
    __syncthreads();
    int x2 = by * 32 + tx, y2 = bx * 32 + ty;
#pragma unroll
    for (int j = 0; j < 4; j++)
      o[(y2 + 8 * j) * EMB + x2] = f2bf(tile[tx][ty + 8 * j]);
  } else {
    int idx = (bid - 8192) * 256 + tid;
    int delta = idx - 2048;
    int bucket = (delta > 0) ? 16 : 0;
    int rp = (delta < 0) ? -delta : delta;
    int bl;
    if (rp < 8) bl = rp;
    else bl = 8 + (rp >= 12) + (rp >= 16) + (rp >= 23) + (rp >= 32) + (rp >= 46) + (rp >= 64) + (rp >= 91);
    bucket += bl;
#pragma unroll
    for (int h = 0; h < NH; h++)
      lut[h * 4096 + idx] = rel[bucket * NH + h];
  }
}

// ---------------- fused QKV GEMM + bias writer (grid-partitioned) ----------------
// blocks [0,768): 128x128 GEMM tiles of C[4096,3072] = Xb @ WqkvT^T
//   which = nBase>>10: 0 -> Q (bf16, pre-scaled log2e), 1 -> K, 2 -> V^T [B,H,D,S]
// blocks [768,1024): position_bias writer (independent, memory-bound, NT stores) —
//   co-resident in the 4th block slot per CU, overlapping writes with GEMM compute.
__global__ __launch_bounds__(256) void gemm_qkv(const unsigned short* __restrict__ A,
                                                const unsigned short* __restrict__ BT,
                                                unsigned short* __restrict__ oQ,
                                                unsigned short* __restrict__ oK,
                                                unsigned short* __restrict__ oV,
                                                const float* __restrict__ lut,
                                                float* __restrict__ bias_out) {
  __shared__ __align__(16) unsigned short As[128 * 64];
  __shared__ __align__(16) unsigned short Bs[128 * 64];
  const int tid = threadIdx.x;
  const int id = blockIdx.x;
  if (id >= 768) {
    // ---- bias path: 256 blocks x 256 threads x 256 float4 = 16.78M float4 ----
    const int bb = id - 768;
#pragma unroll 4
    for (int e = 0; e < 256; e++) {
      int i = (bb << 16) + (e << 8) + tid;
      int h = i >> 20;
      int rem = i & 1048575;
      int q = rem >> 9;
      int k4 = (rem & 511) << 2;
      const float* lr = lut + h * 4096 + (k4 - q + 2048);
      floatx4 v = (floatx4){lr[0], lr[1], lr[2], lr[3]};
      __builtin_nontemporal_store(v, (floatx4*)&bias_out[(size_t)i * 4]);
    }
    return;
  }
  const int wave = tid >> 6, lane = tid & 63;
  const int quad = lane >> 4, lm = lane & 15;
  const int wm = wave & 1, wn = wave >> 1;
  const int mBase = (id / 24) * 128, nBase = (id % 24) * 128;
  const int gg = (lane & 7) ^ (lane >> 3);
  const int srow = lane >> 3;
  floatx4 acc[4][4];
#pragma unroll
  for (int i = 0; i < 4; i++)
#pragma unroll
    for (int j = 0; j < 4; j++) acc[i][j] = (floatx4){0.f, 0.f, 0.f, 0.f};

  for (int kt = 0; kt < 16; kt++) {
    int k0 = kt * 64;
    __syncthreads();
#pragma unroll
    for (int c = 0; c < 4; c++) {
      int chunk = wave * 4 + c;
      int row = chunk * 8 + srow;
      gld_lds16(&A[(size_t)(mBase + row) * 1024 + k0 + gg * 8], &As[chunk * 512]);
      gld_lds16(&BT[(size_t)(nBase + row) * 1024 + k0 + gg * 8], &Bs[chunk * 512]);
    }
    __syncthreads();
#pragma unroll
    for (int hh = 0; hh < 2; hh++) {
      bf16x8 af[4], bfr[4];
#pragma unroll
      for (int i = 0; i < 4; i++)
        af[i] = *(const bf16x8*)&As[(wm * 64 + i * 16 + lm) * 64 + (((hh << 2) + quad) ^ (lm & 7)) * 8];
#pragma unroll
      for (int j = 0; j < 4; j++)
        bfr[j] = *(const bf16x8*)&Bs[(wn * 64 + j * 16 + lm) * 64 + (((hh << 2) + quad) ^ (lm & 7)) * 8];
#pragma unroll
      for (int i = 0; i < 4; i++)
#pragma unroll
        for (int j = 0; j < 4; j++)
          acc[i][j] = __builtin_amdgcn_mfma_f32_16x16x32_bf16(af[i], bfr[j], acc[i][j], 0, 0, 0);
    }
  }
  const int which = nBase >> 10;  // block-uniform
  if (which == 2) {
#pragma unroll
    for (int i = 0; i < 4; i++)
#pragma unroll
      for (int j = 0; j < 4; j++) {
        int hd = (nBase - 2048) + wn * 64 + j * 16 + lm;
        int h = hd >> 6, d = hd & 63;
        int m = mBase + wm * 64 + i * 16 + quad * 4;
        int b = m >> 11, s = m & 2047;
        union { unsigned short u[4]; uint2 v; } pk;
#pragma unroll
        for (int r = 0; r < 4; r++) pk.u[r] = f2bf(acc[i][j][r]);
        *(uint2*)&oV[(((size_t)(b * NH + h) * 64 + d) * S_LEN) + s] = pk.v;
      }
  } else {
#pragma unroll
    for (int i = 0; i < 4; i++)
#pragma unroll
      for (int j = 0; j < 4; j++)
#pragma unroll
        for (int r = 0; r < 4; r++) {
          int row = mBase + wm * 64 + i * 16 + quad * 4 + r;
          int col = nBase + wn * 64 + j * 16 + lm;
          int b = row >> 11, s = row & 2047;
          int cw = col & 1023;
          int h = cw >> 6, d = cw & 63;
          float v = acc[i][j][r];
          if (which == 0) v *= L2E;  // pre-scale Q for exp2-based softmax
          unsigned short sv = f2bf(v);
          if (which == 0) oQ[(((size_t)(b * NH + h) * S_LEN + s) * 64) + d] = sv;
          else            oK[(((size_t)(b * NH + h) * S_LEN + s) * 64) + d] = sv;
        }
  }
}

// ---------------- GEMM out-proj: f32 [M,1024] ----------------
__global__ __launch_bounds__(256) void gemm_out(const unsigned short* __restrict__ A,
                                                const unsigned short* __restrict__ BT,
                                                float* __restrict__ oF) {
  __shared__ __align__(16) unsigned short As[128 * 64];
  __shared__ __align__(16) unsigned short Bs[128 * 64];
  const int tid = threadIdx.x;
  const int wave = tid >> 6, lane = tid & 63;
  const int quad = lane >> 4, lm = lane & 15;
  const int wm = wave & 1, wn = wave >> 1;
  const int mBase = blockIdx.y * 128, nBase = blockIdx.x * 128;
  const int gg = (lane & 7) ^ (lane >> 3);
  const int srow = lane >> 3;
  floatx4 acc[4][4];
#pragma unroll
  for (int i = 0; i < 4; i++)
#pragma unroll
    for (int j = 0; j < 4; j++) acc[i][j] = (floatx4){0.f, 0.f, 0.f, 0.f};

  for (int kt = 0; kt < 16; kt++) {
    int k0 = kt * 64;
    __syncthreads();
#pragma unroll
    for (int c = 0; c < 4; c++) {
      int chunk = wave * 4 + c;
      int row = chunk * 8 + srow;
      gld_lds16(&A[(size_t)(mBase + row) * 1024 + k0 + gg * 8], &As[chunk * 512]);
      gld_lds16(&BT[(size_t)(nBase + row) * 1024 + k0 + gg * 8], &Bs[chunk * 512]);
    }
    __syncthreads();
#pragma unroll
    for (int hh = 0; hh < 2; hh++) {
      bf16x8 af[4], bfr[4];
#pragma unroll
      for (int i = 0; i < 4; i++)
        af[i] = *(const bf16x8*)&As[(wm * 64 + i * 16 + lm) * 64 + (((hh << 2) + quad) ^ (lm & 7)) * 8];
#pragma unroll
      for (int j = 0; j < 4; j++)
        bfr[j] = *(const bf16x8*)&Bs[(wn * 64 + j * 16 + lm) * 64 + (((hh << 2) + quad) ^ (lm & 7)) * 8];
#pragma unroll
      for (int i = 0; i < 4; i++)
#pragma unroll
        for (int j = 0; j < 4; j++)
          acc[i][j] = __builtin_amdgcn_mfma_f32_16x16x32_bf16(af[i], bfr[j], acc[i][j], 0, 0, 0);
    }
  }
#pragma unroll
  for (int i = 0; i < 4; i++)
#pragma unroll
    for (int j = 0; j < 4; j++)
#pragma unroll
      for (int r = 0; r < 4; r++) {
        int row = mBase + wm * 64 + i * 16 + quad * 4 + r;
        int col = nBase + wn * 64 + j * 16 + lm;
        oF[(size_t)row * 1024 + col] = acc[i][j][r];
      }
}

// ---------------- flash attention: single-barrier double-buffered K-loop ----------------
__global__ __launch_bounds__(512, 4) void attn_kernel(const unsigned short* __restrict__ Qb,
                                                      const unsigned short* __restrict__ Kb,
                                                      const unsigned short* __restrict__ Vtb,
                                                      const float* __restrict__ lut,
                                                      unsigned short* __restrict__ Ob) {
  __shared__ __align__(16) unsigned short Kl[2][2][2048];  // [half][buf][32 k x 64 d]
  __shared__ __align__(16) unsigned short Vl[2][2][2048];  // [half][buf][64 d x 32 k]
  __shared__ __align__(16) unsigned short Pl[8][16 * 40];  // P: 16 q x 32 k, stride 40
  __shared__ float lutS[512];
  const int tid = threadIdx.x;
  const int wave = tid >> 6, lane = tid & 63;
  const int quad = lane >> 4, lm = lane & 15;
  const int ws = wave & 3, half = wave >> 2;
  const int ii = blockIdx.x;
  const int bh = (ii & 7) * 4 + ((ii >> 3) & 3);
  const int qTile = (ii >> 5) * 128;
  const int b = bh >> 4, h = bh & 15;
  const unsigned short* Qp = Qb + (size_t)bh * S_LEN * 64;
  const unsigned short* Kp = Kb + (size_t)bh * S_LEN * 64;
  const unsigned short* Vp = Vtb + (size_t)bh * 64 * S_LEN;
  const float* lrow = lut + h * 4096;
  const float cneg = lrow[0] * L2E, cpos = lrow[4095] * L2E;
  const int srow = lane >> 3;
  const int gg = (lane & 7) ^ (srow & 7);
  const int vrow = lane >> 2;
  const int vgg = (lane & 3) ^ ((lane >> 3) & 3);
  const int qw = qTile + ws * 32;

  lutS[tid & 511] = lrow[2048 - 256 + (tid & 511)] * L2E;

  bf16x8 aq[2][2];
#pragma unroll
  for (int g = 0; g < 2; g++)
#pragma unroll
    for (int hh = 0; hh < 2; hh++)
      aq[g][hh] = *(const bf16x8*)&Qp[(qw + g * 16 + lm) * 64 + hh * 32 + quad * 8];

  floatx4 accO[2][4];
#pragma unroll
  for (int g = 0; g < 2; g++)
#pragma unroll
    for (int d = 0; d < 4; d++) accO[g][d] = (floatx4){0.f, 0.f, 0.f, 0.f};
  float lp[2] = {0.f, 0.f};

  unsigned short* Pw = Pl[wave];
  const int vswz = ((lm >> 1) & 3);

  {
    const int kBase = half << 10;
    gld_lds16(&Kp[(size_t)(kBase + ws * 8 + srow) * 64 + gg * 8], &Kl[half][0][ws * 512]);
    gld_lds16(&Vp[(size_t)(ws * 16 + vrow) * S_LEN + kBase + vgg * 8], &Vl[half][0][ws * 512]);
  }

  for (int ktl = 0; ktl < 32; ktl++) {
    const int buf = ktl & 1;
    const int kBase = (half << 10) + ktl * 32;
    __syncthreads();
    if (ktl < 31) {
      const int kn = kBase + 32;
      gld_lds16(&Kp[(size_t)(kn + ws * 8 + srow) * 64 + gg * 8], &Kl[half][buf ^ 1][ws * 512]);
      gld_lds16(&Vp[(size_t)(ws * 16 + vrow) * S_LEN + kn + vgg * 8], &Vl[half][buf ^ 1][ws * 512]);
    }
    const unsigned short* Kbuf = Kl[half][buf];
    const unsigned short* Vbuf = Vl[half][buf];

    const bool farTile = (kBase + 122 <= qTile) || (kBase >= qTile + 218);
    const float cfar = (kBase < qTile) ? cneg : cpos;

    floatx4 s4[2][2];
#pragma unroll
    for (int nt = 0; nt < 2; nt++) {
      int rbase = (nt * 16 + lm) * 64;
      bf16x8 kf0 = *(const bf16x8*)&Kbuf[rbase + ((quad ^ (lm & 7)) << 3)];
      bf16x8 kf1 = *(const bf16x8*)&Kbuf[rbase + (((4 + quad) ^ (lm & 7)) << 3)];
#pragma unroll
      for (int g = 0; g < 2; g++) {
        floatx4 z = (floatx4){0.f, 0.f, 0.f, 0.f};
        z = __builtin_amdgcn_mfma_f32_16x16x32_bf16(kf0, aq[g][0], z, 0, 0, 0);
        z = __builtin_amdgcn_mfma_f32_16x16x32_bf16(kf1, aq[g][1], z, 0, 0, 0);
        s4[g][nt] = z;
      }
    }

    bf16x8 pa[2];
#pragma unroll
    for (int g = 0; g < 2; g++) {
      const int b0 = kBase + quad * 4 - (qw + g * 16 + lm) + 256;
      float psum = 0.f;
#pragma unroll
      for (int nt = 0; nt < 2; nt++) {
        union { unsigned short u[4]; uint2 v; } pk;
#pragma unroll
        for (int r = 0; r < 4; r++) {
          float sv;
          if (farTile) sv = s4[g][nt][r] + cfar;
          else         sv = s4[g][nt][r] + lutS[b0 + nt * 16 + r];
          float p = __builtin_amdgcn_exp2f(sv);
          psum += p;
          pk.u[r] = f2bf_fast(p);
        }
        *(uint2*)&Pw[lm * 40 + nt * 16 + quad * 4] = pk.v;
      }
      lp[g] += psum;
      pa[g] = *(const bf16x8*)&Pw[lm * 40 + quad * 8];
    }

#pragma unroll
    for (int d = 0; d < 4; d++) {
      bf16x8 vf = *(const bf16x8*)&Vbuf[(d * 16 + lm) * 32 + ((quad ^ vswz) << 3)];
      accO[0][d] = __builtin_amdgcn_mfma_f32_16x16x32_bf16(pa[0], vf, accO[0][d], 0, 0, 0);
      accO[1][d] = __builtin_amdgcn_mfma_f32_16x16x32_bf16(pa[1], vf, accO[1][d], 0, 0, 0);
    }
  }

#pragma unroll
  for (int g = 0; g < 2; g++) {
    lp[g] += __shfl_xor(lp[g], 16, 64);
    lp[g] += __shfl_xor(lp[g], 32, 64);
  }

  __syncthreads();
  float* Ox = (ws < 2) ? ((float*)&Kl[0][0][0]) + ws * 2048 : ((float*)&Vl[0][0][0]) + (ws - 2) * 2048;
  float* lpf = (float*)&Pl[0][0];
  if (half == 1) {
#pragma unroll
    for (int g = 0; g < 2; g++) {
#pragma unroll
      for (int d = 0; d < 4; d++)
#pragma unroll
        for (int r = 0; r < 4; r++)
          Ox[(g * 16 + quad * 4 + r) * 64 + d * 16 + lm] = accO[g][d][r];
      if (quad == 0) lpf[ws * 32 + g * 16 + lm] = lp[g];
    }
  }
  __syncthreads();
  if (half == 0) {
    float ltot[2];
#pragma unroll
    for (int g = 0; g < 2; g++) ltot[g] = lp[g] + lpf[ws * 32 + g * 16 + lm];
#pragma unroll
    for (int g = 0; g < 2; g++) {
      float linv[4];
#pragma unroll
      for (int r = 0; r < 4; r++) linv[r] = 1.f / __shfl(ltot[g], quad * 4 + r, 64);
#pragma unroll
      for (int d = 0; d < 4; d++)
#pragma unroll
        for (int r = 0; r < 4; r++) {
          float val = accO[g][d][r] + Ox[(g * 16 + quad * 4 + r) * 64 + d * 16 + lm];
          int q = qw + g * 16 + quad * 4 + r;
          int col = h * 64 + d * 16 + lm;
          Ob[((size_t)(b * S_LEN + q)) * 1024 + col] = f2bf_fast(val * linv[r]);
        }
    }
  }
}

extern "C" void kernel_launch(void* const* d_in, const int* in_sizes, int n_in,
                              void* d_out, int out_size, void* d_ws, size_t ws_size,
                              hipStream_t stream) {
  const float* X   = (const float*)d_in[0];
  const float* Wq  = (const float*)d_in[1];
  const float* Wk  = (const float*)d_in[2];
  const float* Wv  = (const float*)d_in[3];
  const float* Wo  = (const float*)d_in[4];
  const float* rel = (const float*)d_in[5];
  float* out = (float*)d_out;           // [2,2048,1024]
  float* bias_out = out + 4194304;      // [1,16,2048,2048]

  char* ws = (char*)d_ws;
  unsigned short* Xb  = (unsigned short*)(ws);
  unsigned short* WT  = (unsigned short*)(ws + (size_t)(8u << 20));   // Wq|Wk|Wv|Wo transposed
  unsigned short* Qb  = (unsigned short*)(ws + (size_t)(16u << 20));
  unsigned short* Kb  = (unsigned short*)(ws + (size_t)(24u << 20));
  unsigned short* Vtb = (unsigned short*)(ws + (size_t)(32u << 20));
  unsigned short* Ob  = (unsigned short*)(ws + (size_t)(40u << 20));
  float* lut          = (float*)(ws + (size_t)(48u << 20));

  prep_kernel<<<8208, 256, 0, stream>>>(X, Wq, Wk, Wv, Wo, rel, Xb, WT, lut);
  gemm_qkv<<<1024, 256, 0, stream>>>(Xb, WT, Qb, Kb, Vtb, lut, bias_out);
  attn_kernel<<<512, 512, 0, stream>>>(Qb, Kb, Vtb, lut, Ob);
  gemm_out<<<dim3(8, 32), 256, 0, stream>>>(Ob, WT + 3 * 1048576, out);
}

// Round 12
// 408.417 us; speedup vs baseline: 1.2721x; 1.0237x over previous
//
#include <hip/hip_runtime.h>
#include <stdint.h>

#define S_LEN 2048
#define NH 16
#define EMB 1024
#define L2E 1.44269504f

typedef __attribute__((ext_vector_type(8))) short bf16x8;
typedef __attribute__((ext_vector_type(4))) float floatx4;
typedef const __attribute__((address_space(1))) unsigned int* gas_u32p;
typedef __attribute__((address_space(3))) unsigned int* las_u32p;

static __device__ __forceinline__ void gld_lds16(const void* g, void* l) {
  __builtin_amdgcn_global_load_lds((gas_u32p)g, (las_u32p)l, 16, 0, 0);
}

static __device__ __forceinline__ unsigned short f2bf(float f) {
  unsigned int u = __float_as_uint(f);
  unsigned int r = (u + 0x7FFFu + ((u >> 16) & 1u)) >> 16;
  return (unsigned short)r;
}
static __device__ __forceinline__ unsigned short f2bf_fast(float f) {
  return (unsigned short)((__float_as_uint(f) + 0x8000u) >> 16);
}

// shared bias-writer block body: writes 64K float4s starting at block index bb
static __device__ __forceinline__ void bias_block(int bb, int tid,
                                                  const float* __restrict__ lut,
                                                  float* __restrict__ bias_out) {
#pragma unroll 4
  for (int e = 0; e < 256; e++) {
    int i = (bb << 16) + (e << 8) + tid;
    int h = i >> 20;
    int rem = i & 1048575;
    int q = rem >> 9;
    int k4 = (rem & 511) << 2;
    const float* lr = lut + h * 4096 + (k4 - q + 2048);
    floatx4 v = (floatx4){lr[0], lr[1], lr[2], lr[3]};
    __builtin_nontemporal_store(v, (floatx4*)&bias_out[(size_t)i * 4]);
  }
}

// ---------------- fused prep: cast X, transpose 4 weights, build LUT ----------------
__global__ __launch_bounds__(256) void prep_kernel(const float* __restrict__ X,
                                                   const float* __restrict__ Wq,
                                                   const float* __restrict__ Wk,
                                                   const float* __restrict__ Wv,
                                                   const float* __restrict__ Wo,
                                                   const float* __restrict__ rel,
                                                   unsigned short* __restrict__ Xb,
                                                   unsigned short* __restrict__ WT,
                                                   float* __restrict__ lut) {
  __shared__ float tile[32][33];
  const int bid = blockIdx.x, tid = threadIdx.x;
  if (bid < 4096) {
    int i = bid * 256 + tid;
    float4 v = ((const float4*)X)[i];
    ushort4 o;
    o.x = f2bf(v.x); o.y = f2bf(v.y); o.z = f2bf(v.z); o.w = f2bf(v.w);
    ((ushort4*)Xb)[i] = o;
  } else if (bid < 8192) {
    int w = (bid - 4096) >> 10, t = (bid - 4096) & 1023;
    const float* in = (w == 0) ? Wq : (w == 1) ? Wk : (w == 2) ? Wv : Wo;
    unsigned short* o = WT + (size_t)w * 1048576;
    int bx = t & 31, by = t >> 5;
    int tx = tid & 31, ty = tid >> 5;
    int x = bx * 32 + tx, y0 = by * 32 + ty;
#pragma unroll
    for (int j = 0; j < 4; j++)
      tile[ty + 8 * j][tx] = in[(y0 + 8 * j) * EMB + x];
    __syncthreads();
    int x2 = by * 32 + tx, y2 = bx * 32 + ty;
#pragma unroll
    for (int j = 0; j < 4; j++)
      o[(y2 + 8 * j) * EMB + x2] = f2bf(tile[tx][ty + 8 * j]);
  } else {
    int idx = (bid - 8192) * 256 + tid;
    int delta = idx - 2048;
    int bucket = (delta > 0) ? 16 : 0;
    int rp = (delta < 0) ? -delta : delta;
    int bl;
    if (rp < 8) bl = rp;
    else bl = 8 + (rp >= 12) + (rp >= 16) + (rp >= 23) + (rp >= 32) + (rp >= 46) + (rp >= 64) + (rp >= 91);
    bucket += bl;
#pragma unroll
    for (int h = 0; h < NH; h++)
      lut[h * 4096 + idx] = rel[bucket * NH + h];
  }
}

// ---------------- fused QKV GEMM + bias writer part 1 (grid-partitioned) ----------------
// blocks [0,768): 128x128 GEMM tiles; blocks [768,928): bias blocks 0..159 (~167 MB,
// hidden under the GEMM's ~27 us of MFMA).
__global__ __launch_bounds__(256) void gemm_qkv(const unsigned short* __restrict__ A,
                                                const unsigned short* __restrict__ BT,
                                                unsigned short* __restrict__ oQ,
                                                unsigned short* __restrict__ oK,
                                                unsigned short* __restrict__ oV,
                                                const float* __restrict__ lut,
                                                float* __restrict__ bias_out) {
  __shared__ __align__(16) unsigned short As[128 * 64];
  __shared__ __align__(16) unsigned short Bs[128 * 64];
  const int tid = threadIdx.x;
  const int id = blockIdx.x;
  if (id >= 768) {
    bias_block(id - 768, tid, lut, bias_out);
    return;
  }
  const int wave = tid >> 6, lane = tid & 63;
  const int quad = lane >> 4, lm = lane & 15;
  const int wm = wave & 1, wn = wave >> 1;
  const int mBase = (id / 24) * 128, nBase = (id % 24) * 128;
  const int gg = (lane & 7) ^ (lane >> 3);
  const int srow = lane >> 3;
  floatx4 acc[4][4];
#pragma unroll
  for (int i = 0; i < 4; i++)
#pragma unroll
    for (int j = 0; j < 4; j++) acc[i][j] = (floatx4){0.f, 0.f, 0.f, 0.f};

  for (int kt = 0; kt < 16; kt++) {
    int k0 = kt * 64;
    __syncthreads();
#pragma unroll
    for (int c = 0; c < 4; c++) {
      int chunk = wave * 4 + c;
      int row = chunk * 8 + srow;
      gld_lds16(&A[(size_t)(mBase + row) * 1024 + k0 + gg * 8], &As[chunk * 512]);
      gld_lds16(&BT[(size_t)(nBase + row) * 1024 + k0 + gg * 8], &Bs[chunk * 512]);
    }
    __syncthreads();
#pragma unroll
    for (int hh = 0; hh < 2; hh++) {
      bf16x8 af[4], bfr[4];
#pragma unroll
      for (int i = 0; i < 4; i++)
        af[i] = *(const bf16x8*)&As[(wm * 64 + i * 16 + lm) * 64 + (((hh << 2) + quad) ^ (lm & 7)) * 8];
#pragma unroll
      for (int j = 0; j < 4; j++)
        bfr[j] = *(const bf16x8*)&Bs[(wn * 64 + j * 16 + lm) * 64 + (((hh << 2) + quad) ^ (lm & 7)) * 8];
#pragma unroll
      for (int i = 0; i < 4; i++)
#pragma unroll
        for (int j = 0; j < 4; j++)
          acc[i][j] = __builtin_amdgcn_mfma_f32_16x16x32_bf16(af[i], bfr[j], acc[i][j], 0, 0, 0);
    }
  }
  const int which = nBase >> 10;  // block-uniform
  if (which == 2) {
#pragma unroll
    for (int i = 0; i < 4; i++)
#pragma unroll
      for (int j = 0; j < 4; j++) {
        int hd = (nBase - 2048) + wn * 64 + j * 16 + lm;
        int h = hd >> 6, d = hd & 63;
        int m = mBase + wm * 64 + i * 16 + quad * 4;
        int b = m >> 11, s = m & 2047;
        union { unsigned short u[4]; uint2 v; } pk;
#pragma unroll
        for (int r = 0; r < 4; r++) pk.u[r] = f2bf(acc[i][j][r]);
        *(uint2*)&oV[(((size_t)(b * NH + h) * 64 + d) * S_LEN) + s] = pk.v;
      }
  } else {
#pragma unroll
    for (int i = 0; i < 4; i++)
#pragma unroll
      for (int j = 0; j < 4; j++)
#pragma unroll
        for (int r = 0; r < 4; r++) {
          int row = mBase + wm * 64 + i * 16 + quad * 4 + r;
          int col = nBase + wn * 64 + j * 16 + lm;
          int b = row >> 11, s = row & 2047;
          int cw = col & 1023;
          int h = cw >> 6, d = cw & 63;
          float v = acc[i][j][r];
          if (which == 0) v *= L2E;  // pre-scale Q for exp2-based softmax
          unsigned short sv = f2bf(v);
          if (which == 0) oQ[(((size_t)(b * NH + h) * S_LEN + s) * 64) + d] = sv;
          else            oK[(((size_t)(b * NH + h) * S_LEN + s) * 64) + d] = sv;
        }
  }
}

// ---------------- GEMM out-proj + bias writer part 2 ----------------
// blocks [0,256): 128x128 GEMM tiles of out[4096,1024]; blocks [256,352): bias blocks 160..255.
__global__ __launch_bounds__(256) void gemm_out(const unsigned short* __restrict__ A,
                                                const unsigned short* __restrict__ BT,
                                                float* __restrict__ oF,
                                                const float* __restrict__ lut,
                                                float* __restrict__ bias_out) {
  __shared__ __align__(16) unsigned short As[128 * 64];
  __shared__ __align__(16) unsigned short Bs[128 * 64];
  const int tid = threadIdx.x;
  const int id = blockIdx.x;
  if (id >= 256) {
    bias_block(160 + (id - 256), tid, lut, bias_out);
    return;
  }
  const int wave = tid >> 6, lane = tid & 63;
  const int quad = lane >> 4, lm = lane & 15;
  const int wm = wave & 1, wn = wave >> 1;
  const int mBase = (id >> 3) * 128, nBase = (id & 7) * 128;
  const int gg = (lane & 7) ^ (lane >> 3);
  const int srow = lane >> 3;
  floatx4 acc[4][4];
#pragma unroll
  for (int i = 0; i < 4; i++)
#pragma unroll
    for (int j = 0; j < 4; j++) acc[i][j] = (floatx4){0.f, 0.f, 0.f, 0.f};

  for (int kt = 0; kt < 16; kt++) {
    int k0 = kt * 64;
    __syncthreads();
#pragma unroll
    for (int c = 0; c < 4; c++) {
      int chunk = wave * 4 + c;
      int row = chunk * 8 + srow;
      gld_lds16(&A[(size_t)(mBase + row) * 1024 + k0 + gg * 8], &As[chunk * 512]);
      gld_lds16(&BT[(size_t)(nBase + row) * 1024 + k0 + gg * 8], &Bs[chunk * 512]);
    }
    __syncthreads();
#pragma unroll
    for (int hh = 0; hh < 2; hh++) {
      bf16x8 af[4], bfr[4];
#pragma unroll
      for (int i = 0; i < 4; i++)
        af[i] = *(const bf16x8*)&As[(wm * 64 + i * 16 + lm) * 64 + (((hh << 2) + quad) ^ (lm & 7)) * 8];
#pragma unroll
      for (int j = 0; j < 4; j++)
        bfr[j] = *(const bf16x8*)&Bs[(wn * 64 + j * 16 + lm) * 64 + (((hh << 2) + quad) ^ (lm & 7)) * 8];
#pragma unroll
      for (int i = 0; i < 4; i++)
#pragma unroll
        for (int j = 0; j < 4; j++)
          acc[i][j] = __builtin_amdgcn_mfma_f32_16x16x32_bf16(af[i], bfr[j], acc[i][j], 0, 0, 0);
    }
  }
#pragma unroll
  for (int i = 0; i < 4; i++)
#pragma unroll
    for (int j = 0; j < 4; j++)
#pragma unroll
      for (int r = 0; r < 4; r++) {
        int row = mBase + wm * 64 + i * 16 + quad * 4 + r;
        int col = nBase + wn * 64 + j * 16 + lm;
        oF[(size_t)row * 1024 + col] = acc[i][j][r];
      }
}

// ---------------- flash attention: single-barrier double-buffered K-loop ----------------
__global__ __launch_bounds__(512, 4) void attn_kernel(const unsigned short* __restrict__ Qb,
                                                      const unsigned short* __restrict__ Kb,
                                                      const unsigned short* __restrict__ Vtb,
                                                      const float* __restrict__ lut,
                                                      unsigned short* __restrict__ Ob) {
  __shared__ __align__(16) unsigned short Kl[2][2][2048];  // [half][buf][32 k x 64 d]
  __shared__ __align__(16) unsigned short Vl[2][2][2048];  // [half][buf][64 d x 32 k]
  __shared__ __align__(16) unsigned short Pl[8][16 * 40];  // P: 16 q x 32 k, stride 40
  __shared__ float lutS[512];
  const int tid = threadIdx.x;
  const int wave = tid >> 6, lane = tid & 63;
  const int quad = lane >> 4, lm = lane & 15;
  const int ws = wave & 3, half = wave >> 2;
  const int ii = blockIdx.x;
  const int bh = (ii & 7) * 4 + ((ii >> 3) & 3);
  const int qTile = (ii >> 5) * 128;
  const int b = bh >> 4, h = bh & 15;
  const unsigned short* Qp = Qb + (size_t)bh * S_LEN * 64;
  const unsigned short* Kp = Kb + (size_t)bh * S_LEN * 64;
  const unsigned short* Vp = Vtb + (size_t)bh * 64 * S_LEN;
  const float* lrow = lut + h * 4096;
  const float cneg = lrow[0] * L2E, cpos = lrow[4095] * L2E;
  const int srow = lane >> 3;
  const int gg = (lane & 7) ^ (srow & 7);
  const int vrow = lane >> 2;
  const int vgg = (lane & 3) ^ ((lane >> 3) & 3);
  const int qw = qTile + ws * 32;

  lutS[tid & 511] = lrow[2048 - 256 + (tid & 511)] * L2E;

  bf16x8 aq[2][2];
#pragma unroll
  for (int g = 0; g < 2; g++)
#pragma unroll
    for (int hh = 0; hh < 2; hh++)
      aq[g][hh] = *(const bf16x8*)&Qp[(qw + g * 16 + lm) * 64 + hh * 32 + quad * 8];

  floatx4 accO[2][4];
#pragma unroll
  for (int g = 0; g < 2; g++)
#pragma unroll
    for (int d = 0; d < 4; d++) accO[g][d] = (floatx4){0.f, 0.f, 0.f, 0.f};
  float lp[2] = {0.f, 0.f};

  unsigned short* Pw = Pl[wave];
  const int vswz = ((lm >> 1) & 3);

  {
    const int kBase = half << 10;
    gld_lds16(&Kp[(size_t)(kBase + ws * 8 + srow) * 64 + gg * 8], &Kl[half][0][ws * 512]);
    gld_lds16(&Vp[(size_t)(ws * 16 + vrow) * S_LEN + kBase + vgg * 8], &Vl[half][0][ws * 512]);
  }

  for (int ktl = 0; ktl < 32; ktl++) {
    const int buf = ktl & 1;
    const int kBase = (half << 10) + ktl * 32;
    __syncthreads();
    if (ktl < 31) {
      const int kn = kBase + 32;
      gld_lds16(&Kp[(size_t)(kn + ws * 8 + srow) * 64 + gg * 8], &Kl[half][buf ^ 1][ws * 512]);
      gld_lds16(&Vp[(size_t)(ws * 16 + vrow) * S_LEN + kn + vgg * 8], &Vl[half][buf ^ 1][ws * 512]);
    }
    const unsigned short* Kbuf = Kl[half][buf];
    const unsigned short* Vbuf = Vl[half][buf];

    const bool farTile = (kBase + 122 <= qTile) || (kBase >= qTile + 218);
    const float cfar = (kBase < qTile) ? cneg : cpos;

    floatx4 s4[2][2];
#pragma unroll
    for (int nt = 0; nt < 2; nt++) {
      int rbase = (nt * 16 + lm) * 64;
      bf16x8 kf0 = *(const bf16x8*)&Kbuf[rbase + ((quad ^ (lm & 7)) << 3)];
      bf16x8 kf1 = *(const bf16x8*)&Kbuf[rbase + (((4 + quad) ^ (lm & 7)) << 3)];
#pragma unroll
      for (int g = 0; g < 2; g++) {
        floatx4 z = (floatx4){0.f, 0.f, 0.f, 0.f};
        z = __builtin_amdgcn_mfma_f32_16x16x32_bf16(kf0, aq[g][0], z, 0, 0, 0);
        z = __builtin_amdgcn_mfma_f32_16x16x32_bf16(kf1, aq[g][1], z, 0, 0, 0);
        s4[g][nt] = z;
      }
    }

    bf16x8 pa[2];
#pragma unroll
    for (int g = 0; g < 2; g++) {
      const int b0 = kBase + quad * 4 - (qw + g * 16 + lm) + 256;
      float psum = 0.f;
#pragma unroll
      for (int nt = 0; nt < 2; nt++) {
        union { unsigned short u[4]; uint2 v; } pk;
#pragma unroll
        for (int r = 0; r < 4; r++) {
          float sv;
          if (farTile) sv = s4[g][nt][r] + cfar;
          else         sv = s4[g][nt][r] + lutS[b0 + nt * 16 + r];
          float p = __builtin_amdgcn_exp2f(sv);
          psum += p;
          pk.u[r] = f2bf_fast(p);
        }
        *(uint2*)&Pw[lm * 40 + nt * 16 + quad * 4] = pk.v;
      }
      lp[g] += psum;
      pa[g] = *(const bf16x8*)&Pw[lm * 40 + quad * 8];
    }

#pragma unroll
    for (int d = 0; d < 4; d++) {
      bf16x8 vf = *(const bf16x8*)&Vbuf[(d * 16 + lm) * 32 + ((quad ^ vswz) << 3)];
      accO[0][d] = __builtin_amdgcn_mfma_f32_16x16x32_bf16(pa[0], vf, accO[0][d], 0, 0, 0);
      accO[1][d] = __builtin_amdgcn_mfma_f32_16x16x32_bf16(pa[1], vf, accO[1][d], 0, 0, 0);
    }
  }

#pragma unroll
  for (int g = 0; g < 2; g++) {
    lp[g] += __shfl_xor(lp[g], 16, 64);
    lp[g] += __shfl_xor(lp[g], 32, 64);
  }

  __syncthreads();
  float* Ox = (ws < 2) ? ((float*)&Kl[0][0][0]) + ws * 2048 : ((float*)&Vl[0][0][0]) + (ws - 2) * 2048;
  float* lpf = (float*)&Pl[0][0];
  if (half == 1) {
#pragma unroll
    for (int g = 0; g < 2; g++) {
#pragma unroll
      for (int d = 0; d < 4; d++)
#pragma unroll
        for (int r = 0; r < 4; r++)
          Ox[(g * 16 + quad * 4 + r) * 64 + d * 16 + lm] = accO[g][d][r];
      if (quad == 0) lpf[ws * 32 + g * 16 + lm] = lp[g];
    }
  }
  __syncthreads();
  if (half == 0) {
    float ltot[2];
#pragma unroll
    for (int g = 0; g < 2; g++) ltot[g] = lp[g] + lpf[ws * 32 + g * 16 + lm];
#pragma unroll
    for (int g = 0; g < 2; g++) {
      float linv[4];
#pragma unroll
      for (int r = 0; r < 4; r++) linv[r] = 1.f / __shfl(ltot[g], quad * 4 + r, 64);
#pragma unroll
      for (int d = 0; d < 4; d++)
#pragma unroll
        for (int r = 0; r < 4; r++) {
          float val = accO[g][d][r] + Ox[(g * 16 + quad * 4 + r) * 64 + d * 16 + lm];
          int q = qw + g * 16 + quad * 4 + r;
          int col = h * 64 + d * 16 + lm;
          Ob[((size_t)(b * S_LEN + q)) * 1024 + col] = f2bf_fast(val * linv[r]);
        }
    }
  }
}

extern "C" void kernel_launch(void* const* d_in, const int* in_sizes, int n_in,
                              void* d_out, int out_size, void* d_ws, size_t ws_size,
                              hipStream_t stream) {
  const float* X   = (const float*)d_in[0];
  const float* Wq  = (const float*)d_in[1];
  const float* Wk  = (const float*)d_in[2];
  const float* Wv  = (const float*)d_in[3];
  const float* Wo  = (const float*)d_in[4];
  const float* rel = (const float*)d_in[5];
  float* out = (float*)d_out;           // [2,2048,1024]
  float* bias_out = out + 4194304;      // [1,16,2048,2048]

  char* ws = (char*)d_ws;
  unsigned short* Xb  = (unsigned short*)(ws);
  unsigned short* WT  = (unsigned short*)(ws + (size_t)(8u << 20));   // Wq|Wk|Wv|Wo transposed
  unsigned short* Qb  = (unsigned short*)(ws + (size_t)(16u << 20));
  unsigned short* Kb  = (unsigned short*)(ws + (size_t)(24u << 20));
  unsigned short* Vtb = (unsigned short*)(ws + (size_t)(32u << 20));
  unsigned short* Ob  = (unsigned short*)(ws + (size_t)(40u << 20));
  float* lut          = (float*)(ws + (size_t)(48u << 20));

  prep_kernel<<<8208, 256, 0, stream>>>(X, Wq, Wk, Wv, Wo, rel, Xb, WT, lut);
  gemm_qkv<<<928, 256, 0, stream>>>(Xb, WT, Qb, Kb, Vtb, lut, bias_out);
  attn_kernel<<<512, 512, 0, stream>>>(Qb, Kb, Vtb, lut, Ob);
  gemm_out<<<352, 256, 0, stream>>>(Ob, WT + 3 * 1048576, out, lut, bias_out);
}